// Round 2
// baseline (1745.724 us; speedup 1.0000x reference)
//
#include <hip/hip_runtime.h>

#define NNODES 50000
#define NEDGES 800000
#define NTOT   (NEDGES + NNODES)   // edges + self loops
#define F_IN   50
#define HEADS  4
#define C1     64
#define HC1    256                 // HEADS*C1
#define NC     121
#define HC3    484                 // HEADS*NC

// ---------------------------------------------------------------- CSR build
__global__ void count_kernel(const int* __restrict__ ei, int* __restrict__ cnt) {
    int i = blockIdx.x * blockDim.x + threadIdx.x;
    if (i >= NTOT) return;
    int d = (i < NEDGES) ? ei[NEDGES + i] : (i - NEDGES);
    if ((unsigned)d >= NNODES) d = 0;   // safety clamp
    atomicAdd(&cnt[d], 1);
}

__global__ void scan_kernel(const int* __restrict__ cnt, int* __restrict__ row_ptr,
                            int* __restrict__ cursor, int n) {
    __shared__ int buf[1024];
    __shared__ int carry;
    int tid = threadIdx.x;
    if (tid == 0) carry = 0;
    __syncthreads();
    for (int base = 0; base < n; base += 1024) {
        int i = base + tid;
        int v = (i < n) ? cnt[i] : 0;
        buf[tid] = v;
        __syncthreads();
        for (int off = 1; off < 1024; off <<= 1) {
            int t = (tid >= off) ? buf[tid - off] : 0;
            __syncthreads();
            buf[tid] += t;
            __syncthreads();
        }
        int excl = carry + buf[tid] - v;
        if (i < n) { row_ptr[i] = excl; cursor[i] = excl; }
        __syncthreads();
        if (tid == 0) carry += buf[1023];
        __syncthreads();
    }
    if (tid == 0) row_ptr[n] = carry;
}

__global__ void scatter_kernel(const int* __restrict__ ei, int* __restrict__ cursor,
                               int* __restrict__ csr_src) {
    int i = blockIdx.x * blockDim.x + threadIdx.x;
    if (i >= NTOT) return;
    int s, d;
    if (i < NEDGES) { s = ei[i]; d = ei[NEDGES + i]; }
    else            { s = d = i - NEDGES; }
    if ((unsigned)d >= NNODES) d = 0;
    if ((unsigned)s >= NNODES) s = 0;
    int pos = atomicAdd(&cursor[d], 1);
    csr_src[pos] = s;
}

// ---------------------------------------------------------------- GEMM (f32)
#define GTM 64
#define GTN 64
#define GTK 32
__global__ __launch_bounds__(256)
void gemm_bias_kernel(const float* __restrict__ A, const float* __restrict__ B,
                      const float* __restrict__ bias, float* __restrict__ Cout,
                      int M, int Nn, int K) {
    __shared__ float As[GTK][GTM];
    __shared__ float Bs[GTK][GTN];
    int tid = threadIdx.x;
    int tx = tid & 15, ty = tid >> 4;
    int m0 = blockIdx.y * GTM, n0 = blockIdx.x * GTN;
    float c[4][4] = {};
    for (int k0 = 0; k0 < K; k0 += GTK) {
        for (int l = tid; l < GTM * GTK; l += 256) {
            int m = l >> 5, k = l & 31;
            float v = 0.f;
            if (m0 + m < M && k0 + k < K) v = A[(size_t)(m0 + m) * K + k0 + k];
            As[k][m] = v;
        }
        for (int l = tid; l < GTK * GTN; l += 256) {
            int k = l >> 6, n = l & 63;
            float v = 0.f;
            if (k0 + k < K && n0 + n < Nn) v = B[(size_t)(k0 + k) * Nn + n0 + n];
            Bs[k][n] = v;
        }
        __syncthreads();
        #pragma unroll
        for (int k = 0; k < GTK; ++k) {
            float a0 = As[k][ty * 4 + 0], a1 = As[k][ty * 4 + 1];
            float a2 = As[k][ty * 4 + 2], a3 = As[k][ty * 4 + 3];
            float b0 = Bs[k][tx * 4 + 0], b1 = Bs[k][tx * 4 + 1];
            float b2 = Bs[k][tx * 4 + 2], b3 = Bs[k][tx * 4 + 3];
            c[0][0] += a0 * b0; c[0][1] += a0 * b1; c[0][2] += a0 * b2; c[0][3] += a0 * b3;
            c[1][0] += a1 * b0; c[1][1] += a1 * b1; c[1][2] += a1 * b2; c[1][3] += a1 * b3;
            c[2][0] += a2 * b0; c[2][1] += a2 * b1; c[2][2] += a2 * b2; c[2][3] += a2 * b3;
            c[3][0] += a3 * b0; c[3][1] += a3 * b1; c[3][2] += a3 * b2; c[3][3] += a3 * b3;
        }
        __syncthreads();
    }
    #pragma unroll
    for (int i = 0; i < 4; ++i) {
        int row = m0 + ty * 4 + i;
        if (row >= M) continue;
        #pragma unroll
        for (int j = 0; j < 4; ++j) {
            int col = n0 + tx * 4 + j;
            if (col >= Nn) continue;
            float v = c[i][j];
            if (bias) v += bias[col];
            Cout[(size_t)row * Nn + col] = v;
        }
    }
}

// ---------------------------------------------------------------- attention logits
__global__ __launch_bounds__(64)
void attn_logits_kernel(const float* __restrict__ h, const float* __restrict__ a_s,
                        const float* __restrict__ a_d,
                        float* __restrict__ als, float* __restrict__ ald, int C) {
    int n = blockIdx.x, lane = threadIdx.x;
    int HC = HEADS * C;
    float ps[HEADS] = {}, pd[HEADS] = {};
    #pragma unroll
    for (int hh = 0; hh < HEADS; ++hh) {
        for (int c = lane; c < C; c += 64) {
            float hv = h[(size_t)n * HC + hh * C + c];
            ps[hh] += hv * a_s[hh * C + c];
            pd[hh] += hv * a_d[hh * C + c];
        }
    }
    #pragma unroll
    for (int off = 32; off; off >>= 1) {
        #pragma unroll
        for (int hh = 0; hh < HEADS; ++hh) {
            ps[hh] += __shfl_xor(ps[hh], off);
            pd[hh] += __shfl_xor(pd[hh], off);
        }
    }
    if (lane == 0) {
        #pragma unroll
        for (int hh = 0; hh < HEADS; ++hh) {
            als[n * HEADS + hh] = ps[hh];
            ald[n * HEADS + hh] = pd[hh];
        }
    }
}

__device__ __forceinline__ float lrelu(float x) { return x > 0.f ? x : 0.2f * x; }

// ---------------------------------------------------------------- aggregation (concat layers, fused residual+ReLU)
__global__ __launch_bounds__(64)
void agg_concat_kernel(const float* __restrict__ h,
                       const float* __restrict__ als, const float* __restrict__ ald,
                       const int* __restrict__ row_ptr, const int* __restrict__ csr_src,
                       const float* __restrict__ resid, float* __restrict__ xnext) {
    int d = blockIdx.x, lane = threadIdx.x;
    int beg = row_ptr[d], end = row_ptr[d + 1];
    float aldd[HEADS];
    #pragma unroll
    for (int hh = 0; hh < HEADS; ++hh) aldd[hh] = ald[d * HEADS + hh];
    float mx[HEADS] = {-1e30f, -1e30f, -1e30f, -1e30f};
    for (int i = beg + lane; i < end; i += 64) {
        int s = csr_src[i];
        #pragma unroll
        for (int hh = 0; hh < HEADS; ++hh)
            mx[hh] = fmaxf(mx[hh], lrelu(als[s * HEADS + hh] + aldd[hh]));
    }
    #pragma unroll
    for (int off = 32; off; off >>= 1)
        #pragma unroll
        for (int hh = 0; hh < HEADS; ++hh) mx[hh] = fmaxf(mx[hh], __shfl_xor(mx[hh], off));
    float den[HEADS] = {};
    for (int i = beg + lane; i < end; i += 64) {
        int s = csr_src[i];
        #pragma unroll
        for (int hh = 0; hh < HEADS; ++hh)
            den[hh] += __expf(lrelu(als[s * HEADS + hh] + aldd[hh]) - mx[hh]);
    }
    #pragma unroll
    for (int off = 32; off; off >>= 1)
        #pragma unroll
        for (int hh = 0; hh < HEADS; ++hh) den[hh] += __shfl_xor(den[hh], off);
    float acc[HEADS] = {};
    for (int i = beg; i < end; ++i) {
        int s = csr_src[i];
        #pragma unroll
        for (int hh = 0; hh < HEADS; ++hh) {
            float alpha = __expf(lrelu(als[s * HEADS + hh] + aldd[hh]) - mx[hh]) / den[hh];
            acc[hh] += alpha * h[(size_t)s * HC1 + hh * C1 + lane];
        }
    }
    #pragma unroll
    for (int hh = 0; hh < HEADS; ++hh) {
        size_t idx = (size_t)d * HC1 + hh * C1 + lane;
        float v = resid[idx] + acc[hh];
        xnext[idx] = fmaxf(v, 0.f);            // ReLU (layers 1 & 2)
    }
}

// ---------------------------------------------------------------- final layer (mean over heads)
__global__ __launch_bounds__(64)
void agg_final_kernel(const float* __restrict__ h3,
                      const float* __restrict__ als, const float* __restrict__ ald,
                      const int* __restrict__ row_ptr, const int* __restrict__ csr_src,
                      const float* __restrict__ resid, float* __restrict__ out) {
    int d = blockIdx.x, lane = threadIdx.x;
    int beg = row_ptr[d], end = row_ptr[d + 1];
    float aldd[HEADS];
    #pragma unroll
    for (int hh = 0; hh < HEADS; ++hh) aldd[hh] = ald[d * HEADS + hh];
    float mx[HEADS] = {-1e30f, -1e30f, -1e30f, -1e30f};
    for (int i = beg + lane; i < end; i += 64) {
        int s = csr_src[i];
        #pragma unroll
        for (int hh = 0; hh < HEADS; ++hh)
            mx[hh] = fmaxf(mx[hh], lrelu(als[s * HEADS + hh] + aldd[hh]));
    }
    #pragma unroll
    for (int off = 32; off; off >>= 1)
        #pragma unroll
        for (int hh = 0; hh < HEADS; ++hh) mx[hh] = fmaxf(mx[hh], __shfl_xor(mx[hh], off));
    float den[HEADS] = {};
    for (int i = beg + lane; i < end; i += 64) {
        int s = csr_src[i];
        #pragma unroll
        for (int hh = 0; hh < HEADS; ++hh)
            den[hh] += __expf(lrelu(als[s * HEADS + hh] + aldd[hh]) - mx[hh]);
    }
    #pragma unroll
    for (int off = 32; off; off >>= 1)
        #pragma unroll
        for (int hh = 0; hh < HEADS; ++hh) den[hh] += __shfl_xor(den[hh], off);
    bool two = (lane + 64) < NC;
    float acc0[HEADS] = {}, acc1[HEADS] = {};
    for (int i = beg; i < end; ++i) {
        int s = csr_src[i];
        #pragma unroll
        for (int hh = 0; hh < HEADS; ++hh) {
            float alpha = __expf(lrelu(als[s * HEADS + hh] + aldd[hh]) - mx[hh]) / den[hh];
            acc0[hh] += alpha * h3[(size_t)s * HC3 + hh * NC + lane];
            if (two)
                acc1[hh] += alpha * h3[(size_t)s * HC3 + hh * NC + lane + 64];
        }
    }
    {
        float v = (acc0[0] + acc0[1] + acc0[2] + acc0[3]) * 0.25f + resid[(size_t)d * NC + lane];
        out[(size_t)d * NC + lane] = v;
    }
    if (two) {
        float v = (acc1[0] + acc1[1] + acc1[2] + acc1[3]) * 0.25f + resid[(size_t)d * NC + lane + 64];
        out[(size_t)d * NC + lane + 64] = v;
    }
}

// ---------------------------------------------------------------- launch
extern "C" void kernel_launch(void* const* d_in, const int* in_sizes, int n_in,
                              void* d_out, int out_size, void* d_ws, size_t ws_size,
                              hipStream_t stream) {
    const float* x0   = (const float*)d_in[0];
    const int*   ei   = (const int*)d_in[1];
    const float* W1   = (const float*)d_in[2];
    const float* as1  = (const float*)d_in[3];
    const float* ad1  = (const float*)d_in[4];
    const float* res1 = (const float*)d_in[5];
    const float* b1   = (const float*)d_in[6];
    const float* W2   = (const float*)d_in[7];
    const float* as2  = (const float*)d_in[8];
    const float* ad2  = (const float*)d_in[9];
    const float* res2 = (const float*)d_in[10];
    const float* b2   = (const float*)d_in[11];
    const float* W3   = (const float*)d_in[12];
    const float* as3  = (const float*)d_in[13];
    const float* ad3  = (const float*)d_in[14];
    const float* res3 = (const float*)d_in[15];
    const float* b3   = (const float*)d_in[16];

    char* p = (char*)d_ws;
    auto alloc = [&](size_t bytes) -> void* {
        void* r = (void*)p;
        p += (bytes + 255) & ~(size_t)255;
        return r;
    };
    int*   cnt     = (int*)alloc((size_t)NNODES * 4);
    int*   row_ptr = (int*)alloc((size_t)(NNODES + 1) * 4);
    int*   cursor  = (int*)alloc((size_t)NNODES * 4);
    int*   csr_src = (int*)alloc((size_t)NTOT * 4);
    float* als     = (float*)alloc((size_t)NNODES * HEADS * 4);
    float* ald     = (float*)alloc((size_t)NNODES * HEADS * 4);
    float* hbuf    = (float*)alloc((size_t)NNODES * HC3 * 4);   // 96.8 MB
    float* resid   = (float*)alloc((size_t)NNODES * HC1 * 4);   // 51.2 MB
    float* xbuf    = (float*)alloc((size_t)NNODES * HC1 * 4);   // 51.2 MB (x1 then x2)

    hipMemsetAsync(cnt, 0, (size_t)NNODES * 4, stream);

    int tb = 256;
    count_kernel<<<(NTOT + tb - 1) / tb, tb, 0, stream>>>(ei, cnt);
    scan_kernel<<<1, 1024, 0, stream>>>(cnt, row_ptr, cursor, NNODES);
    scatter_kernel<<<(NTOT + tb - 1) / tb, tb, 0, stream>>>(ei, cursor, csr_src);

    auto gemm = [&](const float* A, const float* B, const float* bias,
                    float* Cptr, int M, int Nn, int K) {
        dim3 g((Nn + GTN - 1) / GTN, (M + GTM - 1) / GTM);
        gemm_bias_kernel<<<g, 256, 0, stream>>>(A, B, bias, Cptr, M, Nn, K);
    };

    // ---- layer 1  (x1 -> xbuf)
    gemm(x0, W1, nullptr, hbuf, NNODES, HC1, F_IN);
    gemm(x0, res1, b1, resid, NNODES, HC1, F_IN);
    attn_logits_kernel<<<NNODES, 64, 0, stream>>>(hbuf, as1, ad1, als, ald, C1);
    agg_concat_kernel<<<NNODES, 64, 0, stream>>>(hbuf, als, ald, row_ptr, csr_src, resid, xbuf);

    // ---- layer 2  (reads xbuf=x1; agg overwrites xbuf with x2 — safe: agg reads only hbuf/resid)
    gemm(xbuf, W2, nullptr, hbuf, NNODES, HC1, HC1);
    gemm(xbuf, res2, b2, resid, NNODES, HC1, HC1);
    attn_logits_kernel<<<NNODES, 64, 0, stream>>>(hbuf, as2, ad2, als, ald, C1);
    agg_concat_kernel<<<NNODES, 64, 0, stream>>>(hbuf, als, ald, row_ptr, csr_src, resid, xbuf);

    // ---- layer 3
    gemm(xbuf, W3, nullptr, hbuf, NNODES, HC3, HC1);
    gemm(xbuf, res3, b3, resid, NNODES, NC, HC1);
    attn_logits_kernel<<<NNODES, 64, 0, stream>>>(hbuf, as3, ad3, als, ald, NC);
    agg_final_kernel<<<NNODES, 64, 0, stream>>>(hbuf, als, ald, row_ptr, csr_src, resid, (float*)d_out);
}

// Round 3
// 1172.315 us; speedup vs baseline: 1.4891x; 1.4891x over previous
//
#include <hip/hip_runtime.h>

#define NNODES 50000
#define NEDGES 800000
#define NTOT   (NEDGES + NNODES)   // edges + self loops
#define F_IN   50
#define KPAD1  64                  // F_IN padded to 64 for MFMA GEMM
#define HEADS  4
#define C1     64
#define HC1    256                 // HEADS*C1
#define NC     121
#define HC3    484                 // HEADS*NC

typedef unsigned short ushort_t;
typedef __attribute__((ext_vector_type(8))) unsigned short ushort8;
typedef __attribute__((ext_vector_type(8))) __bf16 bf16x8;
typedef __attribute__((ext_vector_type(4))) float f32x4;

__device__ __forceinline__ ushort_t f2bf(float f) {
    union { float f; unsigned int u; } v; v.f = f;
    unsigned int u = v.u;
    unsigned int r = (u + 0x7fffu + ((u >> 16) & 1u)) >> 16;   // RNE
    return (ushort_t)r;
}

// ---------------------------------------------------------------- CSR build
__global__ void count_kernel(const int* __restrict__ ei, int* __restrict__ cnt) {
    int i = blockIdx.x * blockDim.x + threadIdx.x;
    if (i >= NTOT) return;
    int d = (i < NEDGES) ? ei[NEDGES + i] : (i - NEDGES);
    if ((unsigned)d >= NNODES) d = 0;
    atomicAdd(&cnt[d], 1);
}

__global__ void scan_kernel(const int* __restrict__ cnt, int* __restrict__ row_ptr,
                            int* __restrict__ cursor, int n) {
    __shared__ int buf[1024];
    __shared__ int carry;
    int tid = threadIdx.x;
    if (tid == 0) carry = 0;
    __syncthreads();
    for (int base = 0; base < n; base += 1024) {
        int i = base + tid;
        int v = (i < n) ? cnt[i] : 0;
        buf[tid] = v;
        __syncthreads();
        for (int off = 1; off < 1024; off <<= 1) {
            int t = (tid >= off) ? buf[tid - off] : 0;
            __syncthreads();
            buf[tid] += t;
            __syncthreads();
        }
        int excl = carry + buf[tid] - v;
        if (i < n) { row_ptr[i] = excl; cursor[i] = excl; }
        __syncthreads();
        if (tid == 0) carry += buf[1023];
        __syncthreads();
    }
    if (tid == 0) row_ptr[n] = carry;
}

__global__ void scatter_kernel(const int* __restrict__ ei, int* __restrict__ cursor,
                               int* __restrict__ csr_src) {
    int i = blockIdx.x * blockDim.x + threadIdx.x;
    if (i >= NTOT) return;
    int s, d;
    if (i < NEDGES) { s = ei[i]; d = ei[NEDGES + i]; }
    else            { s = d = i - NEDGES; }
    if ((unsigned)d >= NNODES) d = 0;
    if ((unsigned)s >= NNODES) s = 0;
    int pos = atomicAdd(&cursor[d], 1);
    csr_src[pos] = s;
}

// ---------------------------------------------------------------- dtype converts
// f32 [M,Kin] -> bf16 [M,Kout], zero-padded in K
__global__ void conv_pad_kernel(const float* __restrict__ in, ushort_t* __restrict__ out,
                                int M, int Kin, int Kout) {
    int i = blockIdx.x * blockDim.x + threadIdx.x;
    if (i >= M * Kout) return;
    int m = i / Kout, k = i - m * Kout;
    out[i] = (k < Kin) ? f2bf(in[(size_t)m * Kin + k]) : (ushort_t)0;
}

// f32 W [K,N] -> bf16 W^T [N,Kpad], zero-padded in K
__global__ void conv_wt_kernel(const float* __restrict__ W, ushort_t* __restrict__ Wt,
                               int K, int N, int Kpad) {
    int i = blockIdx.x * blockDim.x + threadIdx.x;
    if (i >= N * Kpad) return;
    int n = i / Kpad, k = i - n * Kpad;
    Wt[i] = (k < K) ? f2bf(W[(size_t)k * N + n]) : (ushort_t)0;
}

// ---------------------------------------------------------------- MFMA GEMM
// C[M,N] (f32, +bias) = A[M,K](bf16) * Bt[N,K](bf16)^T.   K % 64 == 0.
#define BM 128
#define BN 128
#define BK 64
#define LDP (BK + 8)               // LDS row pitch in shorts (144 B: 16B-aligned, conflict-free)

__global__ __launch_bounds__(256)
void gemm_mfma_kernel(const ushort_t* __restrict__ A, const ushort_t* __restrict__ Bt,
                      const float* __restrict__ bias, float* __restrict__ C,
                      int M, int N, int K) {
    __shared__ ushort_t As[BM * LDP];
    __shared__ ushort_t Bs[BN * LDP];
    int tid = threadIdx.x;
    int lane = tid & 63;
    int wid = tid >> 6;
    int wm = (wid & 1) * 64, wn = (wid >> 1) * 64;
    int l15 = lane & 15;
    int q8 = (lane >> 4) * 8;
    int m0 = blockIdx.y * BM, n0 = blockIdx.x * BN;

    f32x4 acc[4][4] = {};

    for (int k0 = 0; k0 < K; k0 += BK) {
        // stage A-tile and Bt-tile: 128 rows x 64 cols each, 16B chunks
        #pragma unroll
        for (int it = 0; it < 4; ++it) {
            int c = tid + it * 256;          // 0..1023
            int row = c >> 3, c8 = c & 7;
            ushort8 va = (ushort8)0;
            int gm = m0 + row;
            if (gm < M) va = *(const ushort8*)&A[(size_t)gm * K + k0 + c8 * 8];
            *(ushort8*)&As[row * LDP + c8 * 8] = va;
            ushort8 vb = (ushort8)0;
            int gn = n0 + row;
            if (gn < N) vb = *(const ushort8*)&Bt[(size_t)gn * K + k0 + c8 * 8];
            *(ushort8*)&Bs[row * LDP + c8 * 8] = vb;
        }
        __syncthreads();
        #pragma unroll
        for (int kk = 0; kk < BK; kk += 32) {
            bf16x8 af[4], bfr[4];
            #pragma unroll
            for (int mi = 0; mi < 4; ++mi)
                af[mi] = *(const bf16x8*)&As[(wm + mi * 16 + l15) * LDP + kk + q8];
            #pragma unroll
            for (int ni = 0; ni < 4; ++ni)
                bfr[ni] = *(const bf16x8*)&Bs[(wn + ni * 16 + l15) * LDP + kk + q8];
            #pragma unroll
            for (int mi = 0; mi < 4; ++mi)
                #pragma unroll
                for (int ni = 0; ni < 4; ++ni)
                    acc[mi][ni] = __builtin_amdgcn_mfma_f32_16x16x32_bf16(
                        af[mi], bfr[ni], acc[mi][ni], 0, 0, 0);
        }
        __syncthreads();
    }

    // epilogue: D layout col=lane&15, row=(lane>>4)*4+reg
    #pragma unroll
    for (int mi = 0; mi < 4; ++mi) {
        int mbase = m0 + wm + mi * 16 + (lane >> 4) * 4;
        #pragma unroll
        for (int ni = 0; ni < 4; ++ni) {
            int ncol = n0 + wn + ni * 16 + l15;
            if (ncol >= N) continue;
            float bv = bias ? bias[ncol] : 0.f;
            #pragma unroll
            for (int r = 0; r < 4; ++r) {
                int m = mbase + r;
                if (m < M) C[(size_t)m * N + ncol] = acc[mi][ni][r] + bv;
            }
        }
    }
}

// ---------------------------------------------------------------- attention logits
__global__ __launch_bounds__(64)
void attn_logits_kernel(const float* __restrict__ h, const float* __restrict__ a_s,
                        const float* __restrict__ a_d,
                        float* __restrict__ als, float* __restrict__ ald, int C) {
    int n = blockIdx.x, lane = threadIdx.x;
    int HC = HEADS * C;
    float ps[HEADS] = {}, pd[HEADS] = {};
    #pragma unroll
    for (int hh = 0; hh < HEADS; ++hh) {
        for (int c = lane; c < C; c += 64) {
            float hv = h[(size_t)n * HC + hh * C + c];
            ps[hh] += hv * a_s[hh * C + c];
            pd[hh] += hv * a_d[hh * C + c];
        }
    }
    #pragma unroll
    for (int off = 32; off; off >>= 1) {
        #pragma unroll
        for (int hh = 0; hh < HEADS; ++hh) {
            ps[hh] += __shfl_xor(ps[hh], off);
            pd[hh] += __shfl_xor(pd[hh], off);
        }
    }
    if (lane == 0) {
        #pragma unroll
        for (int hh = 0; hh < HEADS; ++hh) {
            als[n * HEADS + hh] = ps[hh];
            ald[n * HEADS + hh] = pd[hh];
        }
    }
}

__device__ __forceinline__ float lrelu(float x) { return x > 0.f ? x : 0.2f * x; }

// ---------------------------------------------------------------- aggregation (concat layers, fused residual+ReLU, bf16 out)
__global__ __launch_bounds__(64)
void agg_concat_kernel(const float* __restrict__ h,
                       const float* __restrict__ als, const float* __restrict__ ald,
                       const int* __restrict__ row_ptr, const int* __restrict__ csr_src,
                       const float* __restrict__ resid, ushort_t* __restrict__ xnext) {
    int d = blockIdx.x, lane = threadIdx.x;
    int beg = row_ptr[d], end = row_ptr[d + 1];
    float aldd[HEADS];
    #pragma unroll
    for (int hh = 0; hh < HEADS; ++hh) aldd[hh] = ald[d * HEADS + hh];
    float mx[HEADS] = {-1e30f, -1e30f, -1e30f, -1e30f};
    for (int i = beg + lane; i < end; i += 64) {
        int s = csr_src[i];
        #pragma unroll
        for (int hh = 0; hh < HEADS; ++hh)
            mx[hh] = fmaxf(mx[hh], lrelu(als[s * HEADS + hh] + aldd[hh]));
    }
    #pragma unroll
    for (int off = 32; off; off >>= 1)
        #pragma unroll
        for (int hh = 0; hh < HEADS; ++hh) mx[hh] = fmaxf(mx[hh], __shfl_xor(mx[hh], off));
    float den[HEADS] = {};
    for (int i = beg + lane; i < end; i += 64) {
        int s = csr_src[i];
        #pragma unroll
        for (int hh = 0; hh < HEADS; ++hh)
            den[hh] += __expf(lrelu(als[s * HEADS + hh] + aldd[hh]) - mx[hh]);
    }
    #pragma unroll
    for (int off = 32; off; off >>= 1)
        #pragma unroll
        for (int hh = 0; hh < HEADS; ++hh) den[hh] += __shfl_xor(den[hh], off);
    float acc[HEADS] = {};
    for (int i = beg; i < end; ++i) {
        int s = csr_src[i];
        #pragma unroll
        for (int hh = 0; hh < HEADS; ++hh) {
            float alpha = __expf(lrelu(als[s * HEADS + hh] + aldd[hh]) - mx[hh]) / den[hh];
            acc[hh] += alpha * h[(size_t)s * HC1 + hh * C1 + lane];
        }
    }
    #pragma unroll
    for (int hh = 0; hh < HEADS; ++hh) {
        size_t idx = (size_t)d * HC1 + hh * C1 + lane;
        float v = fmaxf(resid[idx] + acc[hh], 0.f);   // ReLU (layers 1 & 2)
        xnext[idx] = f2bf(v);
    }
}

// ---------------------------------------------------------------- final layer (mean over heads)
__global__ __launch_bounds__(64)
void agg_final_kernel(const float* __restrict__ h3,
                      const float* __restrict__ als, const float* __restrict__ ald,
                      const int* __restrict__ row_ptr, const int* __restrict__ csr_src,
                      const float* __restrict__ resid, float* __restrict__ out) {
    int d = blockIdx.x, lane = threadIdx.x;
    int beg = row_ptr[d], end = row_ptr[d + 1];
    float aldd[HEADS];
    #pragma unroll
    for (int hh = 0; hh < HEADS; ++hh) aldd[hh] = ald[d * HEADS + hh];
    float mx[HEADS] = {-1e30f, -1e30f, -1e30f, -1e30f};
    for (int i = beg + lane; i < end; i += 64) {
        int s = csr_src[i];
        #pragma unroll
        for (int hh = 0; hh < HEADS; ++hh)
            mx[hh] = fmaxf(mx[hh], lrelu(als[s * HEADS + hh] + aldd[hh]));
    }
    #pragma unroll
    for (int off = 32; off; off >>= 1)
        #pragma unroll
        for (int hh = 0; hh < HEADS; ++hh) mx[hh] = fmaxf(mx[hh], __shfl_xor(mx[hh], off));
    float den[HEADS] = {};
    for (int i = beg + lane; i < end; i += 64) {
        int s = csr_src[i];
        #pragma unroll
        for (int hh = 0; hh < HEADS; ++hh)
            den[hh] += __expf(lrelu(als[s * HEADS + hh] + aldd[hh]) - mx[hh]);
    }
    #pragma unroll
    for (int off = 32; off; off >>= 1)
        #pragma unroll
        for (int hh = 0; hh < HEADS; ++hh) den[hh] += __shfl_xor(den[hh], off);
    bool two = (lane + 64) < NC;
    float acc0[HEADS] = {}, acc1[HEADS] = {};
    for (int i = beg; i < end; ++i) {
        int s = csr_src[i];
        #pragma unroll
        for (int hh = 0; hh < HEADS; ++hh) {
            float alpha = __expf(lrelu(als[s * HEADS + hh] + aldd[hh]) - mx[hh]) / den[hh];
            acc0[hh] += alpha * h3[(size_t)s * HC3 + hh * NC + lane];
            if (two)
                acc1[hh] += alpha * h3[(size_t)s * HC3 + hh * NC + lane + 64];
        }
    }
    {
        float v = (acc0[0] + acc0[1] + acc0[2] + acc0[3]) * 0.25f + resid[(size_t)d * NC + lane];
        out[(size_t)d * NC + lane] = v;
    }
    if (two) {
        float v = (acc1[0] + acc1[1] + acc1[2] + acc1[3]) * 0.25f + resid[(size_t)d * NC + lane + 64];
        out[(size_t)d * NC + lane + 64] = v;
    }
}

// ---------------------------------------------------------------- launch
extern "C" void kernel_launch(void* const* d_in, const int* in_sizes, int n_in,
                              void* d_out, int out_size, void* d_ws, size_t ws_size,
                              hipStream_t stream) {
    const float* x0   = (const float*)d_in[0];
    const int*   ei   = (const int*)d_in[1];
    const float* W1   = (const float*)d_in[2];
    const float* as1  = (const float*)d_in[3];
    const float* ad1  = (const float*)d_in[4];
    const float* res1 = (const float*)d_in[5];
    const float* b1   = (const float*)d_in[6];
    const float* W2   = (const float*)d_in[7];
    const float* as2  = (const float*)d_in[8];
    const float* ad2  = (const float*)d_in[9];
    const float* res2 = (const float*)d_in[10];
    const float* b2   = (const float*)d_in[11];
    const float* W3   = (const float*)d_in[12];
    const float* as3  = (const float*)d_in[13];
    const float* ad3  = (const float*)d_in[14];
    const float* res3 = (const float*)d_in[15];
    const float* b3   = (const float*)d_in[16];

    char* p = (char*)d_ws;
    auto alloc = [&](size_t bytes) -> void* {
        void* r = (void*)p;
        p += (bytes + 255) & ~(size_t)255;
        return r;
    };
    int*      cnt     = (int*)alloc((size_t)NNODES * 4);
    int*      row_ptr = (int*)alloc((size_t)(NNODES + 1) * 4);
    int*      cursor  = (int*)alloc((size_t)NNODES * 4);
    int*      csr_src = (int*)alloc((size_t)NTOT * 4);
    float*    als     = (float*)alloc((size_t)NNODES * HEADS * 4);
    float*    ald     = (float*)alloc((size_t)NNODES * HEADS * 4);
    float*    hbuf    = (float*)alloc((size_t)NNODES * HC3 * 4);   // 96.8 MB
    float*    resid   = (float*)alloc((size_t)NNODES * HC1 * 4);   // 51.2 MB
    ushort_t* xb      = (ushort_t*)alloc((size_t)NNODES * HC1 * 2);// 25.6 MB (x1 then x2, bf16)
    ushort_t* x0b     = (ushort_t*)alloc((size_t)NNODES * KPAD1 * 2);
    ushort_t* W1t     = (ushort_t*)alloc((size_t)HC1 * KPAD1 * 2);
    ushort_t* r1t     = (ushort_t*)alloc((size_t)HC1 * KPAD1 * 2);
    ushort_t* W2t     = (ushort_t*)alloc((size_t)HC1 * HC1 * 2);
    ushort_t* r2t     = (ushort_t*)alloc((size_t)HC1 * HC1 * 2);
    ushort_t* W3t     = (ushort_t*)alloc((size_t)HC3 * HC1 * 2);
    ushort_t* r3t     = (ushort_t*)alloc((size_t)NC * HC1 * 2);

    hipMemsetAsync(cnt, 0, (size_t)NNODES * 4, stream);

    int tb = 256;
    count_kernel<<<(NTOT + tb - 1) / tb, tb, 0, stream>>>(ei, cnt);
    scan_kernel<<<1, 1024, 0, stream>>>(cnt, row_ptr, cursor, NNODES);
    scatter_kernel<<<(NTOT + tb - 1) / tb, tb, 0, stream>>>(ei, cursor, csr_src);

    // converts
    conv_pad_kernel<<<(NNODES * KPAD1 + tb - 1) / tb, tb, 0, stream>>>(x0, x0b, NNODES, F_IN, KPAD1);
    conv_wt_kernel<<<(HC1 * KPAD1 + tb - 1) / tb, tb, 0, stream>>>(W1, W1t, F_IN, HC1, KPAD1);
    conv_wt_kernel<<<(HC1 * KPAD1 + tb - 1) / tb, tb, 0, stream>>>(res1, r1t, F_IN, HC1, KPAD1);
    conv_wt_kernel<<<(HC1 * HC1 + tb - 1) / tb, tb, 0, stream>>>(W2, W2t, HC1, HC1, HC1);
    conv_wt_kernel<<<(HC1 * HC1 + tb - 1) / tb, tb, 0, stream>>>(res2, r2t, HC1, HC1, HC1);
    conv_wt_kernel<<<(HC3 * HC1 + tb - 1) / tb, tb, 0, stream>>>(W3, W3t, HC1, HC3, HC1);
    conv_wt_kernel<<<(NC * HC1 + tb - 1) / tb, tb, 0, stream>>>(res3, r3t, HC1, NC, HC1);

    auto gemm = [&](const ushort_t* A, const ushort_t* Bt, const float* bias,
                    float* Cptr, int M, int Nn, int K) {
        dim3 g((Nn + BN - 1) / BN, (M + BM - 1) / BM);
        gemm_mfma_kernel<<<g, 256, 0, stream>>>(A, Bt, bias, Cptr, M, Nn, K);
    };

    // ---- layer 1  (x1 -> xb)
    gemm(x0b, W1t, nullptr, hbuf, NNODES, HC1, KPAD1);
    gemm(x0b, r1t, b1, resid, NNODES, HC1, KPAD1);
    attn_logits_kernel<<<NNODES, 64, 0, stream>>>(hbuf, as1, ad1, als, ald, C1);
    agg_concat_kernel<<<NNODES, 64, 0, stream>>>(hbuf, als, ald, row_ptr, csr_src, resid, xb);

    // ---- layer 2  (reads xb=x1; agg overwrites xb with x2 — safe: agg reads only hbuf/resid)
    gemm(xb, W2t, nullptr, hbuf, NNODES, HC1, HC1);
    gemm(xb, r2t, b2, resid, NNODES, HC1, HC1);
    attn_logits_kernel<<<NNODES, 64, 0, stream>>>(hbuf, as2, ad2, als, ald, C1);
    agg_concat_kernel<<<NNODES, 64, 0, stream>>>(hbuf, als, ald, row_ptr, csr_src, resid, xb);

    // ---- layer 3
    gemm(xb, W3t, nullptr, hbuf, NNODES, HC3, HC1);
    gemm(xb, r3t, b3, resid, NNODES, NC, HC1);
    attn_logits_kernel<<<NNODES, 64, 0, stream>>>(hbuf, as3, ad3, als, ald, NC);
    agg_final_kernel<<<NNODES, 64, 0, stream>>>(hbuf, als, ald, row_ptr, csr_src, resid, (float*)d_out);
}

// Round 4
// 1061.014 us; speedup vs baseline: 1.6453x; 1.1049x over previous
//
#include <hip/hip_runtime.h>

#define NNODES 50000
#define NEDGES 800000
#define NTOT   (NEDGES + NNODES)   // edges + self loops
#define F_IN   50
#define KPAD1  64                  // F_IN padded to 64
#define HEADS  4
#define C1     64
#define HC1    256                 // HEADS*C1
#define NC     121
#define K1S    320                 // stacked K layer1: 4*64 + 64
#define K3S    1280                // stacked K layer3: 4*256 + 256

typedef unsigned short ushort_t;
typedef __attribute__((ext_vector_type(4))) unsigned short ushort4_t;
typedef __attribute__((ext_vector_type(8))) unsigned short ushort8;
typedef __attribute__((ext_vector_type(8))) __bf16 bf16x8;
typedef __attribute__((ext_vector_type(4))) float f32x4;

__device__ __forceinline__ ushort_t f2bf(float f) {
    union { float f; unsigned int u; } v; v.f = f;
    unsigned int u = v.u;
    return (ushort_t)((u + 0x7fffu + ((u >> 16) & 1u)) >> 16);   // RNE
}
__device__ __forceinline__ float bf2f(ushort_t s) {
    union { unsigned int u; float f; } v; v.u = ((unsigned int)s) << 16;
    return v.f;
}
__device__ __forceinline__ float lrelu(float x) { return x > 0.f ? x : 0.2f * x; }

// ---------------------------------------------------------------- CSR build
__global__ void count_kernel(const int* __restrict__ ei, int* __restrict__ cnt) {
    int i = blockIdx.x * blockDim.x + threadIdx.x;
    if (i >= NTOT) return;
    int d = (i < NEDGES) ? ei[NEDGES + i] : (i - NEDGES);
    if ((unsigned)d >= NNODES) d = 0;
    atomicAdd(&cnt[d], 1);
}

__global__ void scan_kernel(const int* __restrict__ cnt, int* __restrict__ row_ptr,
                            int* __restrict__ cursor, int n) {
    __shared__ int buf[1024];
    __shared__ int carry;
    int tid = threadIdx.x;
    if (tid == 0) carry = 0;
    __syncthreads();
    for (int base = 0; base < n; base += 1024) {
        int i = base + tid;
        int v = (i < n) ? cnt[i] : 0;
        buf[tid] = v;
        __syncthreads();
        for (int off = 1; off < 1024; off <<= 1) {
            int t = (tid >= off) ? buf[tid - off] : 0;
            __syncthreads();
            buf[tid] += t;
            __syncthreads();
        }
        int excl = carry + buf[tid] - v;
        if (i < n) { row_ptr[i] = excl; cursor[i] = excl; }
        __syncthreads();
        if (tid == 0) carry += buf[1023];
        __syncthreads();
    }
    if (tid == 0) row_ptr[n] = carry;
}

__global__ void scatter_kernel(const int* __restrict__ ei, int* __restrict__ cursor,
                               int* __restrict__ csr_src) {
    int i = blockIdx.x * blockDim.x + threadIdx.x;
    if (i >= NTOT) return;
    int s, d;
    if (i < NEDGES) { s = ei[i]; d = ei[NEDGES + i]; }
    else            { s = d = i - NEDGES; }
    if ((unsigned)d >= NNODES) d = 0;
    if ((unsigned)s >= NNODES) s = 0;
    int pos = atomicAdd(&cursor[d], 1);
    csr_src[pos] = s;
}

// ---------------------------------------------------------------- converts / builders
// f32 [M,Kin] -> bf16 [M,Kout], zero-padded
__global__ void conv_pad_kernel(const float* __restrict__ in, ushort_t* __restrict__ out,
                                int M, int Kin, int Kout) {
    int i = blockIdx.x * blockDim.x + threadIdx.x;
    if (i >= M * Kout) return;
    int m = i / Kout, k = i - m * Kout;
    out[i] = (k < Kin) ? f2bf(in[(size_t)m * Kin + k]) : (ushort_t)0;
}

// f32 W [K,N] -> bf16 W^T [N,Kpad]
__global__ void conv_wt_kernel(const float* __restrict__ W, ushort_t* __restrict__ Wt,
                               int K, int N, int Kpad) {
    int i = blockIdx.x * blockDim.x + threadIdx.x;
    if (i >= N * Kpad) return;
    int n = i / Kpad, k = i - n * Kpad;
    Wt[i] = (k < K) ? f2bf(W[(size_t)k * N + n]) : (ushort_t)0;
}

// w[k,h] = sum_c W[k, h*C+c] * a[h,c]; output [Kpad,4] f32, zero-padded
__global__ void build_w_kernel(const float* __restrict__ W, const float* __restrict__ a,
                               float* __restrict__ w, int Kin, int Kpad, int C) {
    int i = blockIdx.x * blockDim.x + threadIdx.x;
    if (i >= Kpad * 4) return;
    int k = i >> 2, h = i & 3;
    float s = 0.f;
    if (k < Kin)
        for (int c = 0; c < C; ++c) s += W[(size_t)k * (4 * C) + h * C + c] * a[h * C + c];
    w[i] = s;
}

// Bt1 [256, 320]: stacked layer-1 weight (block-diag W1 per head | res1), transposed
__global__ void build_bt1_kernel(const float* __restrict__ W1, const float* __restrict__ res1,
                                 ushort_t* __restrict__ Bt1) {
    int i = blockIdx.x * blockDim.x + threadIdx.x;
    if (i >= HC1 * K1S) return;
    int c = i / K1S, kk = i - c * K1S;
    float v = 0.f;
    if (kk < 256) {
        int h = kk >> 6, k = kk & 63;
        if (k < F_IN && (c >> 6) == h) v = W1[(size_t)k * HC1 + c];
    } else {
        int k = kk - 256;
        if (k < F_IN) v = res1[(size_t)k * HC1 + c];
    }
    Bt1[i] = f2bf(v);
}

// Bt3 [121, 1280]: (0.25*W3 per head stacked | res3), transposed
__global__ void build_bt3_kernel(const float* __restrict__ W3, const float* __restrict__ res3,
                                 ushort_t* __restrict__ Bt3) {
    int i = blockIdx.x * blockDim.x + threadIdx.x;
    if (i >= NC * K3S) return;
    int c = i / K3S, kk = i - c * K3S;
    float v;
    if (kk < 1024) {
        int h = kk >> 8, k = kk & 255;
        v = 0.25f * W3[(size_t)k * (HEADS * NC) + h * NC + c];
    } else {
        int k = kk - 1024;
        v = res3[(size_t)k * NC + c];
    }
    Bt3[i] = f2bf(v);
}

// ---------------------------------------------------------------- MFMA GEMM
// C[M,N] = A[M,K](bf16) * Bt[N,K]^T (+bias, opt relu). K % 64 == 0.
#define BM 128
#define BN 128
#define BK 64
#define LDP (BK + 8)

__global__ __launch_bounds__(256)
void gemm_mfma_kernel(const ushort_t* __restrict__ A, const ushort_t* __restrict__ Bt,
                      const float* __restrict__ bias,
                      float* __restrict__ Cf, ushort_t* __restrict__ Cb,
                      int M, int N, int K, int relu) {
    __shared__ ushort_t As[BM * LDP];
    __shared__ ushort_t Bs[BN * LDP];
    int tid = threadIdx.x;
    int lane = tid & 63;
    int wid = tid >> 6;
    int wm = (wid & 1) * 64, wn = (wid >> 1) * 64;
    int l15 = lane & 15;
    int q8 = (lane >> 4) * 8;
    int m0 = blockIdx.y * BM, n0 = blockIdx.x * BN;

    f32x4 acc[4][4] = {};

    for (int k0 = 0; k0 < K; k0 += BK) {
        #pragma unroll
        for (int it = 0; it < 4; ++it) {
            int c = tid + it * 256;
            int row = c >> 3, c8 = c & 7;
            ushort8 va = (ushort8)0;
            int gm = m0 + row;
            if (gm < M) va = *(const ushort8*)&A[(size_t)gm * K + k0 + c8 * 8];
            *(ushort8*)&As[row * LDP + c8 * 8] = va;
            ushort8 vb = (ushort8)0;
            int gn = n0 + row;
            if (gn < N) vb = *(const ushort8*)&Bt[(size_t)gn * K + k0 + c8 * 8];
            *(ushort8*)&Bs[row * LDP + c8 * 8] = vb;
        }
        __syncthreads();
        #pragma unroll
        for (int kk = 0; kk < BK; kk += 32) {
            bf16x8 af[4], bfr[4];
            #pragma unroll
            for (int mi = 0; mi < 4; ++mi)
                af[mi] = *(const bf16x8*)&As[(wm + mi * 16 + l15) * LDP + kk + q8];
            #pragma unroll
            for (int ni = 0; ni < 4; ++ni)
                bfr[ni] = *(const bf16x8*)&Bs[(wn + ni * 16 + l15) * LDP + kk + q8];
            #pragma unroll
            for (int mi = 0; mi < 4; ++mi)
                #pragma unroll
                for (int ni = 0; ni < 4; ++ni)
                    acc[mi][ni] = __builtin_amdgcn_mfma_f32_16x16x32_bf16(
                        af[mi], bfr[ni], acc[mi][ni], 0, 0, 0);
        }
        __syncthreads();
    }

    #pragma unroll
    for (int mi = 0; mi < 4; ++mi) {
        int mbase = m0 + wm + mi * 16 + (lane >> 4) * 4;
        #pragma unroll
        for (int ni = 0; ni < 4; ++ni) {
            int ncol = n0 + wn + ni * 16 + l15;
            if (ncol >= N) continue;
            float bv = bias ? bias[ncol] : 0.f;
            #pragma unroll
            for (int r = 0; r < 4; ++r) {
                int m = mbase + r;
                if (m >= M) continue;
                float v = acc[mi][ni][r] + bv;
                if (relu) v = fmaxf(v, 0.f);
                if (Cf) Cf[(size_t)m * N + ncol] = v;
                else    Cb[(size_t)m * N + ncol] = f2bf(v);
            }
        }
    }
}

// ---------------------------------------------------------------- logits GEMV: als/ald[n,h] = X[n,:]·w[:,h]
__global__ __launch_bounds__(64)
void logits_gemv_kernel(const ushort_t* __restrict__ X, int K,
                        const float* __restrict__ w_as, const float* __restrict__ w_ad,
                        float* __restrict__ als, float* __restrict__ ald) {
    int n = blockIdx.x, lane = threadIdx.x;
    float ps[HEADS] = {}, pd[HEADS] = {};
    for (int k = lane; k < K; k += 64) {
        float xv = bf2f(X[(size_t)n * K + k]);
        #pragma unroll
        for (int h = 0; h < HEADS; ++h) {
            ps[h] += xv * w_as[k * 4 + h];
            pd[h] += xv * w_ad[k * 4 + h];
        }
    }
    #pragma unroll
    for (int off = 32; off; off >>= 1)
        #pragma unroll
        for (int h = 0; h < HEADS; ++h) {
            ps[h] += __shfl_xor(ps[h], off);
            pd[h] += __shfl_xor(pd[h], off);
        }
    if (lane == 0)
        #pragma unroll
        for (int h = 0; h < HEADS; ++h) {
            als[n * HEADS + h] = ps[h];
            ald[n * HEADS + h] = pd[h];
        }
}

// ---------------------------------------------------------------- agg layer 1 (gather x0b, 64 cols)
__global__ __launch_bounds__(64)
void agg1_kernel(const ushort_t* __restrict__ x0b,
                 const float* __restrict__ als, const float* __restrict__ ald,
                 const int* __restrict__ row_ptr, const int* __restrict__ csr_src,
                 ushort_t* __restrict__ aggx) {
    int d = blockIdx.x, lane = threadIdx.x;
    int beg = row_ptr[d], end = row_ptr[d + 1];
    float aldd[HEADS];
    #pragma unroll
    for (int h = 0; h < HEADS; ++h) aldd[h] = ald[d * HEADS + h];
    float mx[HEADS] = {-1e30f, -1e30f, -1e30f, -1e30f};
    for (int i = beg + lane; i < end; i += 64) {
        int s = csr_src[i];
        #pragma unroll
        for (int h = 0; h < HEADS; ++h)
            mx[h] = fmaxf(mx[h], lrelu(als[s * HEADS + h] + aldd[h]));
    }
    #pragma unroll
    for (int off = 32; off; off >>= 1)
        #pragma unroll
        for (int h = 0; h < HEADS; ++h) mx[h] = fmaxf(mx[h], __shfl_xor(mx[h], off));
    float den[HEADS] = {};
    for (int i = beg + lane; i < end; i += 64) {
        int s = csr_src[i];
        #pragma unroll
        for (int h = 0; h < HEADS; ++h)
            den[h] += __expf(lrelu(als[s * HEADS + h] + aldd[h]) - mx[h]);
    }
    #pragma unroll
    for (int off = 32; off; off >>= 1)
        #pragma unroll
        for (int h = 0; h < HEADS; ++h) den[h] += __shfl_xor(den[h], off);
    float acc[HEADS] = {};
    for (int i = beg; i < end; ++i) {
        int s = csr_src[i];
        float xv = bf2f(x0b[(size_t)s * KPAD1 + lane]);
        #pragma unroll
        for (int h = 0; h < HEADS; ++h) {
            float alpha = __expf(lrelu(als[s * HEADS + h] + aldd[h]) - mx[h]) / den[h];
            acc[h] += alpha * xv;
        }
    }
    #pragma unroll
    for (int h = 0; h < HEADS; ++h)
        aggx[(size_t)d * K1S + h * 64 + lane] = f2bf(acc[h]);
    aggx[(size_t)d * K1S + 256 + lane] = x0b[(size_t)d * KPAD1 + lane];
}

// ---------------------------------------------------------------- agg layer 2 (gather h2 bf16, fused resid+ReLU)
__global__ __launch_bounds__(64)
void agg2_kernel(const ushort_t* __restrict__ h,
                 const float* __restrict__ als, const float* __restrict__ ald,
                 const int* __restrict__ row_ptr, const int* __restrict__ csr_src,
                 const float* __restrict__ resid, ushort_t* __restrict__ xnext) {
    int d = blockIdx.x, lane = threadIdx.x;
    int beg = row_ptr[d], end = row_ptr[d + 1];
    float aldd[HEADS];
    #pragma unroll
    for (int h2 = 0; h2 < HEADS; ++h2) aldd[h2] = ald[d * HEADS + h2];
    float mx[HEADS] = {-1e30f, -1e30f, -1e30f, -1e30f};
    for (int i = beg + lane; i < end; i += 64) {
        int s = csr_src[i];
        #pragma unroll
        for (int h2 = 0; h2 < HEADS; ++h2)
            mx[h2] = fmaxf(mx[h2], lrelu(als[s * HEADS + h2] + aldd[h2]));
    }
    #pragma unroll
    for (int off = 32; off; off >>= 1)
        #pragma unroll
        for (int h2 = 0; h2 < HEADS; ++h2) mx[h2] = fmaxf(mx[h2], __shfl_xor(mx[h2], off));
    float den[HEADS] = {};
    for (int i = beg + lane; i < end; i += 64) {
        int s = csr_src[i];
        #pragma unroll
        for (int h2 = 0; h2 < HEADS; ++h2)
            den[h2] += __expf(lrelu(als[s * HEADS + h2] + aldd[h2]) - mx[h2]);
    }
    #pragma unroll
    for (int off = 32; off; off >>= 1)
        #pragma unroll
        for (int h2 = 0; h2 < HEADS; ++h2) den[h2] += __shfl_xor(den[h2], off);
    float acc[HEADS] = {};
    for (int i = beg; i < end; ++i) {
        int s = csr_src[i];
        #pragma unroll
        for (int h2 = 0; h2 < HEADS; ++h2) {
            float alpha = __expf(lrelu(als[s * HEADS + h2] + aldd[h2]) - mx[h2]) / den[h2];
            acc[h2] += alpha * bf2f(h[(size_t)s * HC1 + h2 * C1 + lane]);
        }
    }
    #pragma unroll
    for (int h2 = 0; h2 < HEADS; ++h2) {
        size_t idx = (size_t)d * HC1 + h2 * C1 + lane;
        xnext[idx] = f2bf(fmaxf(resid[idx] + acc[h2], 0.f));
    }
}

// ---------------------------------------------------------------- agg layer 3 (gather x2b, 256 cols, per-head stacked out)
__global__ __launch_bounds__(64)
void agg3_kernel(const ushort_t* __restrict__ x2b,
                 const float* __restrict__ als, const float* __restrict__ ald,
                 const int* __restrict__ row_ptr, const int* __restrict__ csr_src,
                 ushort_t* __restrict__ aggx) {
    int d = blockIdx.x, lane = threadIdx.x;
    int beg = row_ptr[d], end = row_ptr[d + 1];
    float aldd[HEADS];
    #pragma unroll
    for (int h = 0; h < HEADS; ++h) aldd[h] = ald[d * HEADS + h];
    float mx[HEADS] = {-1e30f, -1e30f, -1e30f, -1e30f};
    for (int i = beg + lane; i < end; i += 64) {
        int s = csr_src[i];
        #pragma unroll
        for (int h = 0; h < HEADS; ++h)
            mx[h] = fmaxf(mx[h], lrelu(als[s * HEADS + h] + aldd[h]));
    }
    #pragma unroll
    for (int off = 32; off; off >>= 1)
        #pragma unroll
        for (int h = 0; h < HEADS; ++h) mx[h] = fmaxf(mx[h], __shfl_xor(mx[h], off));
    float den[HEADS] = {};
    for (int i = beg + lane; i < end; i += 64) {
        int s = csr_src[i];
        #pragma unroll
        for (int h = 0; h < HEADS; ++h)
            den[h] += __expf(lrelu(als[s * HEADS + h] + aldd[h]) - mx[h]);
    }
    #pragma unroll
    for (int off = 32; off; off >>= 1)
        #pragma unroll
        for (int h = 0; h < HEADS; ++h) den[h] += __shfl_xor(den[h], off);
    float acc[HEADS][4] = {};
    for (int i = beg; i < end; ++i) {
        int s = csr_src[i];
        ushort4_t xv = *(const ushort4_t*)&x2b[(size_t)s * HC1 + lane * 4];
        float x0 = bf2f(xv.x), x1 = bf2f(xv.y), x2 = bf2f(xv.z), x3 = bf2f(xv.w);
        #pragma unroll
        for (int h = 0; h < HEADS; ++h) {
            float alpha = __expf(lrelu(als[s * HEADS + h] + aldd[h]) - mx[h]) / den[h];
            acc[h][0] += alpha * x0; acc[h][1] += alpha * x1;
            acc[h][2] += alpha * x2; acc[h][3] += alpha * x3;
        }
    }
    #pragma unroll
    for (int h = 0; h < HEADS; ++h) {
        ushort4_t o;
        o.x = f2bf(acc[h][0]); o.y = f2bf(acc[h][1]);
        o.z = f2bf(acc[h][2]); o.w = f2bf(acc[h][3]);
        *(ushort4_t*)&aggx[(size_t)d * K3S + h * HC1 + lane * 4] = o;
    }
    ushort4_t xd = *(const ushort4_t*)&x2b[(size_t)d * HC1 + lane * 4];
    *(ushort4_t*)&aggx[(size_t)d * K3S + 1024 + lane * 4] = xd;
}

// ---------------------------------------------------------------- launch
extern "C" void kernel_launch(void* const* d_in, const int* in_sizes, int n_in,
                              void* d_out, int out_size, void* d_ws, size_t ws_size,
                              hipStream_t stream) {
    const float* x0   = (const float*)d_in[0];
    const int*   ei   = (const int*)d_in[1];
    const float* W1   = (const float*)d_in[2];
    const float* as1  = (const float*)d_in[3];
    const float* ad1  = (const float*)d_in[4];
    const float* res1 = (const float*)d_in[5];
    const float* b1   = (const float*)d_in[6];
    const float* W2   = (const float*)d_in[7];
    const float* as2  = (const float*)d_in[8];
    const float* ad2  = (const float*)d_in[9];
    const float* res2 = (const float*)d_in[10];
    const float* b2   = (const float*)d_in[11];
    const float* W3   = (const float*)d_in[12];
    const float* as3  = (const float*)d_in[13];
    const float* ad3  = (const float*)d_in[14];
    const float* res3 = (const float*)d_in[15];
    const float* b3   = (const float*)d_in[16];

    char* p = (char*)d_ws;
    auto alloc = [&](size_t bytes) -> void* {
        void* r = (void*)p;
        p += (bytes + 255) & ~(size_t)255;
        return r;
    };
    int*      cnt     = (int*)alloc((size_t)NNODES * 4);
    int*      row_ptr = (int*)alloc((size_t)(NNODES + 1) * 4);
    int*      cursor  = (int*)alloc((size_t)NNODES * 4);
    int*      csr_src = (int*)alloc((size_t)NTOT * 4);
    float*    als     = (float*)alloc((size_t)NNODES * HEADS * 4);
    float*    ald     = (float*)alloc((size_t)NNODES * HEADS * 4);
    ushort_t* x0b     = (ushort_t*)alloc((size_t)NNODES * KPAD1 * 2);
    ushort_t* x2      = (ushort_t*)alloc((size_t)NNODES * HC1 * 2);
    ushort_t* Bt1     = (ushort_t*)alloc((size_t)HC1 * K1S * 2);
    ushort_t* W2t     = (ushort_t*)alloc((size_t)HC1 * HC1 * 2);
    ushort_t* r2t     = (ushort_t*)alloc((size_t)HC1 * HC1 * 2);
    ushort_t* Bt3     = (ushort_t*)alloc((size_t)NC * K3S * 2);
    float*    w_as1   = (float*)alloc((size_t)KPAD1 * 4 * 4);
    float*    w_ad1   = (float*)alloc((size_t)KPAD1 * 4 * 4);
    float*    w_as2   = (float*)alloc((size_t)HC1 * 4 * 4);
    float*    w_ad2   = (float*)alloc((size_t)HC1 * 4 * 4);
    float*    w_as3   = (float*)alloc((size_t)HC1 * 4 * 4);
    float*    w_ad3   = (float*)alloc((size_t)HC1 * 4 * 4);
    // big aliased region: layer1/2 temporaries, later reused as aggx3 [N,1280] bf16
    char*     big     = (char*)alloc((size_t)NNODES * K3S * 2);
    ushort_t* aggx1   = (ushort_t*)big;                                  // [N,320] bf16 (32 MB)
    float*    resid   = (float*)(big + (size_t)NNODES * K1S * 2);        // [N,256] f32 (51.2 MB)
    ushort_t* h2      = (ushort_t*)(big + (size_t)NNODES * (K1S * 2 + HC1 * 4));          // [N,256] bf16
    ushort_t* x1      = (ushort_t*)(big + (size_t)NNODES * (K1S * 2 + HC1 * 4 + HC1 * 2));// [N,256] bf16
    ushort_t* aggx3   = (ushort_t*)big;                                  // [N,1280] bf16 (layer 3)

    hipMemsetAsync(cnt, 0, (size_t)NNODES * 4, stream);

    int tb = 256;
    count_kernel<<<(NTOT + tb - 1) / tb, tb, 0, stream>>>(ei, cnt);
    scan_kernel<<<1, 1024, 0, stream>>>(cnt, row_ptr, cursor, NNODES);
    scatter_kernel<<<(NTOT + tb - 1) / tb, tb, 0, stream>>>(ei, cursor, csr_src);

    // converts / weight prep
    conv_pad_kernel<<<(NNODES * KPAD1 + tb - 1) / tb, tb, 0, stream>>>(x0, x0b, NNODES, F_IN, KPAD1);
    build_bt1_kernel<<<(HC1 * K1S + tb - 1) / tb, tb, 0, stream>>>(W1, res1, Bt1);
    conv_wt_kernel<<<(HC1 * HC1 + tb - 1) / tb, tb, 0, stream>>>(W2, W2t, HC1, HC1, HC1);
    conv_wt_kernel<<<(HC1 * HC1 + tb - 1) / tb, tb, 0, stream>>>(res2, r2t, HC1, HC1, HC1);
    build_bt3_kernel<<<(NC * K3S + tb - 1) / tb, tb, 0, stream>>>(W3, res3, Bt3);
    build_w_kernel<<<(KPAD1 * 4 + tb - 1) / tb, tb, 0, stream>>>(W1, as1, w_as1, F_IN, KPAD1, C1);
    build_w_kernel<<<(KPAD1 * 4 + tb - 1) / tb, tb, 0, stream>>>(W1, ad1, w_ad1, F_IN, KPAD1, C1);
    build_w_kernel<<<(HC1 * 4 + tb - 1) / tb, tb, 0, stream>>>(W2, as2, w_as2, HC1, HC1, C1);
    build_w_kernel<<<(HC1 * 4 + tb - 1) / tb, tb, 0, stream>>>(W2, ad2, w_ad2, HC1, HC1, C1);
    build_w_kernel<<<(HC1 * 4 + tb - 1) / tb, tb, 0, stream>>>(W3, as3, w_as3, HC1, HC1, NC);
    build_w_kernel<<<(HC1 * 4 + tb - 1) / tb, tb, 0, stream>>>(W3, ad3, w_ad3, HC1, HC1, NC);

    auto gemm = [&](const ushort_t* A, const ushort_t* Bt, const float* bias,
                    float* Cf, ushort_t* Cb, int M, int Nn, int K, int relu) {
        dim3 g((Nn + BN - 1) / BN, (M + BM - 1) / BM);
        gemm_mfma_kernel<<<g, 256, 0, stream>>>(A, Bt, bias, Cf, Cb, M, Nn, K, relu);
    };

    // ---- layer 1 (aggregate-then-transform)
    logits_gemv_kernel<<<NNODES, 64, 0, stream>>>(x0b, KPAD1, w_as1, w_ad1, als, ald);
    agg1_kernel<<<NNODES, 64, 0, stream>>>(x0b, als, ald, row_ptr, csr_src, aggx1);
    gemm(aggx1, Bt1, b1, nullptr, x1, NNODES, HC1, K1S, 1);   // x1 = relu(agg@W1 + x0@res1 + b1)

    // ---- layer 2 (direct, h2 bf16)
    gemm(x1, W2t, nullptr, nullptr, h2, NNODES, HC1, HC1, 0);
    gemm(x1, r2t, b2, resid, nullptr, NNODES, HC1, HC1, 0);
    logits_gemv_kernel<<<NNODES, 64, 0, stream>>>(x1, HC1, w_as2, w_ad2, als, ald);
    agg2_kernel<<<NNODES, 64, 0, stream>>>(h2, als, ald, row_ptr, csr_src, resid, x2);

    // ---- layer 3 (aggregate-then-transform; aggx3 aliases dead layer-1/2 buffers)
    logits_gemv_kernel<<<NNODES, 64, 0, stream>>>(x2, HC1, w_as3, w_ad3, als, ald);
    agg3_kernel<<<NNODES, 64, 0, stream>>>(x2, als, ald, row_ptr, csr_src, aggx3);
    gemm(aggx3, Bt3, b3, (float*)d_out, nullptr, NNODES, NC, K3S, 0);
}

// Round 5
// 952.437 us; speedup vs baseline: 1.8329x; 1.1140x over previous
//
#include <hip/hip_runtime.h>

#define NNODES 50000
#define NEDGES 800000
#define NTOT   (NEDGES + NNODES)   // edges + self loops
#define F_IN   50
#define KPAD1  64                  // F_IN padded to 64
#define HEADS  4
#define C1     64
#define HC1    256                 // HEADS*C1
#define NC     121
#define K1S    320                 // stacked K layer1: 4*64 + 64
#define K3S    1280                // stacked K layer3: 4*256 + 256
#define N2S    512                 // stacked N layer2: 256 (W2) + 256 (res2)

typedef unsigned short ushort_t;
typedef __attribute__((ext_vector_type(4))) unsigned short ushort4_t;
typedef __attribute__((ext_vector_type(8))) unsigned short ushort8;
typedef __attribute__((ext_vector_type(8))) __bf16 bf16x8;
typedef __attribute__((ext_vector_type(4))) float f32x4;

__device__ __forceinline__ ushort_t f2bf(float f) {
    union { float f; unsigned int u; } v; v.f = f;
    unsigned int u = v.u;
    return (ushort_t)((u + 0x7fffu + ((u >> 16) & 1u)) >> 16);   // RNE
}
__device__ __forceinline__ float bf2f(ushort_t s) {
    union { unsigned int u; float f; } v; v.u = ((unsigned int)s) << 16;
    return v.f;
}
__device__ __forceinline__ float lrelu(float x) { return x > 0.f ? x : 0.2f * x; }

// ---------------------------------------------------------------- CSR build
__global__ void count_kernel(const int* __restrict__ ei, int* __restrict__ cnt) {
    int i = blockIdx.x * blockDim.x + threadIdx.x;
    if (i >= NTOT) return;
    int d = (i < NEDGES) ? ei[NEDGES + i] : (i - NEDGES);
    if ((unsigned)d >= NNODES) d = 0;
    atomicAdd(&cnt[d], 1);
}

#define SCAN_T 1024
__global__ __launch_bounds__(SCAN_T)
void scan_kernel(const int* __restrict__ cnt, int* __restrict__ row_ptr,
                 int* __restrict__ cursor, int n) {
    __shared__ int sums[SCAN_T];
    int tid = threadIdx.x;
    int chunk = (n + SCAN_T - 1) / SCAN_T;
    int lo = tid * chunk;
    int hi = lo + chunk; if (hi > n) hi = n;
    int s = 0;
    for (int i = lo; i < hi; ++i) s += cnt[i];
    sums[tid] = s;
    __syncthreads();
    for (int off = 1; off < SCAN_T; off <<= 1) {
        int t = (tid >= off) ? sums[tid - off] : 0;
        __syncthreads();
        sums[tid] += t;
        __syncthreads();
    }
    int base = tid ? sums[tid - 1] : 0;
    for (int i = lo; i < hi; ++i) {
        int c = cnt[i];
        row_ptr[i] = base; cursor[i] = base;
        base += c;
    }
    if (tid == SCAN_T - 1) row_ptr[n] = sums[SCAN_T - 1];
}

__global__ void scatter_kernel(const int* __restrict__ ei, int* __restrict__ cursor,
                               int* __restrict__ csr_src) {
    int i = blockIdx.x * blockDim.x + threadIdx.x;
    if (i >= NTOT) return;
    int s, d;
    if (i < NEDGES) { s = ei[i]; d = ei[NEDGES + i]; }
    else            { s = d = i - NEDGES; }
    if ((unsigned)d >= NNODES) d = 0;
    if ((unsigned)s >= NNODES) s = 0;
    int pos = atomicAdd(&cursor[d], 1);
    csr_src[pos] = s;
}

// ---------------------------------------------------------------- converts / builders
__global__ void conv_pad_kernel(const float* __restrict__ in, ushort_t* __restrict__ out,
                                int M, int Kin, int Kout) {
    int i = blockIdx.x * blockDim.x + threadIdx.x;
    if (i >= M * Kout) return;
    int m = i / Kout, k = i - m * Kout;
    out[i] = (k < Kin) ? f2bf(in[(size_t)m * Kin + k]) : (ushort_t)0;
}

// w[k,h] = sum_c W[k, h*C+c] * a[h,c]; [Kpad,4] f32
__global__ void build_w_kernel(const float* __restrict__ W, const float* __restrict__ a,
                               float* __restrict__ w, int Kin, int Kpad, int C) {
    int i = blockIdx.x * blockDim.x + threadIdx.x;
    if (i >= Kpad * 4) return;
    int k = i >> 2, h = i & 3;
    float s = 0.f;
    if (k < Kin)
        for (int c = 0; c < C; ++c) s += W[(size_t)k * (4 * C) + h * C + c] * a[h * C + c];
    w[i] = s;
}

// Bt1 [256, 320]: (block-diag W1 per head | res1)^T
__global__ void build_bt1_kernel(const float* __restrict__ W1, const float* __restrict__ res1,
                                 ushort_t* __restrict__ Bt1) {
    int i = blockIdx.x * blockDim.x + threadIdx.x;
    if (i >= HC1 * K1S) return;
    int c = i / K1S, kk = i - c * K1S;
    float v = 0.f;
    if (kk < 256) {
        int h = kk >> 6, k = kk & 63;
        if (k < F_IN && (c >> 6) == h) v = W1[(size_t)k * HC1 + c];
    } else {
        int k = kk - 256;
        if (k < F_IN) v = res1[(size_t)k * HC1 + c];
    }
    Bt1[i] = f2bf(v);
}

// Bt2 [512, 256]: columns 0..255 = W2, 256..511 = res2, transposed
__global__ void build_bt2_kernel(const float* __restrict__ W2, const float* __restrict__ res2,
                                 ushort_t* __restrict__ Bt2) {
    int i = blockIdx.x * blockDim.x + threadIdx.x;
    if (i >= N2S * HC1) return;
    int c = i / HC1, k = i - c * HC1;
    float v = (c < HC1) ? W2[(size_t)k * HC1 + c] : res2[(size_t)k * HC1 + (c - HC1)];
    Bt2[i] = f2bf(v);
}

__global__ void build_bias2_kernel(const float* __restrict__ b2, float* __restrict__ bias512) {
    int i = blockIdx.x * blockDim.x + threadIdx.x;
    if (i >= N2S) return;
    bias512[i] = (i < HC1) ? 0.f : b2[i - HC1];
}

// Bt3 [121, 1280]: (0.25*W3 per head stacked | res3)^T
__global__ void build_bt3_kernel(const float* __restrict__ W3, const float* __restrict__ res3,
                                 ushort_t* __restrict__ Bt3) {
    int i = blockIdx.x * blockDim.x + threadIdx.x;
    if (i >= NC * K3S) return;
    int c = i / K3S, kk = i - c * K3S;
    float v;
    if (kk < 1024) {
        int h = kk >> 8, k = kk & 255;
        v = 0.25f * W3[(size_t)k * (HEADS * NC) + h * NC + c];
    } else {
        int k = kk - 1024;
        v = res3[(size_t)k * NC + c];
    }
    Bt3[i] = f2bf(v);
}

// ---------------------------------------------------------------- MFMA GEMM
#define BM 128
#define BN 128
#define BK 64
#define LDP (BK + 8)

__global__ __launch_bounds__(256)
void gemm_mfma_kernel(const ushort_t* __restrict__ A, const ushort_t* __restrict__ Bt,
                      const float* __restrict__ bias,
                      float* __restrict__ Cf, ushort_t* __restrict__ Cb,
                      int M, int N, int K, int relu) {
    __shared__ ushort_t As[BM * LDP];
    __shared__ ushort_t Bs[BN * LDP];
    int tid = threadIdx.x;
    int lane = tid & 63;
    int wid = tid >> 6;
    int wm = (wid & 1) * 64, wn = (wid >> 1) * 64;
    int l15 = lane & 15;
    int q8 = (lane >> 4) * 8;
    int m0 = blockIdx.y * BM, n0 = blockIdx.x * BN;

    f32x4 acc[4][4] = {};

    for (int k0 = 0; k0 < K; k0 += BK) {
        #pragma unroll
        for (int it = 0; it < 4; ++it) {
            int c = tid + it * 256;
            int row = c >> 3, c8 = c & 7;
            ushort8 va = (ushort8)0;
            int gm = m0 + row;
            if (gm < M) va = *(const ushort8*)&A[(size_t)gm * K + k0 + c8 * 8];
            *(ushort8*)&As[row * LDP + c8 * 8] = va;
            ushort8 vb = (ushort8)0;
            int gn = n0 + row;
            if (gn < N) vb = *(const ushort8*)&Bt[(size_t)gn * K + k0 + c8 * 8];
            *(ushort8*)&Bs[row * LDP + c8 * 8] = vb;
        }
        __syncthreads();
        #pragma unroll
        for (int kk = 0; kk < BK; kk += 32) {
            bf16x8 af[4], bfr[4];
            #pragma unroll
            for (int mi = 0; mi < 4; ++mi)
                af[mi] = *(const bf16x8*)&As[(wm + mi * 16 + l15) * LDP + kk + q8];
            #pragma unroll
            for (int ni = 0; ni < 4; ++ni)
                bfr[ni] = *(const bf16x8*)&Bs[(wn + ni * 16 + l15) * LDP + kk + q8];
            #pragma unroll
            for (int mi = 0; mi < 4; ++mi)
                #pragma unroll
                for (int ni = 0; ni < 4; ++ni)
                    acc[mi][ni] = __builtin_amdgcn_mfma_f32_16x16x32_bf16(
                        af[mi], bfr[ni], acc[mi][ni], 0, 0, 0);
        }
        __syncthreads();
    }

    #pragma unroll
    for (int mi = 0; mi < 4; ++mi) {
        int mbase = m0 + wm + mi * 16 + (lane >> 4) * 4;
        #pragma unroll
        for (int ni = 0; ni < 4; ++ni) {
            int ncol = n0 + wn + ni * 16 + l15;
            if (ncol >= N) continue;
            float bv = bias ? bias[ncol] : 0.f;
            #pragma unroll
            for (int r = 0; r < 4; ++r) {
                int m = mbase + r;
                if (m >= M) continue;
                float v = acc[mi][ni][r] + bv;
                if (relu) v = fmaxf(v, 0.f);
                if (Cf) Cf[(size_t)m * N + ncol] = v;
                else    Cb[(size_t)m * N + ncol] = f2bf(v);
            }
        }
    }
}

// ---------------------------------------------------------------- logits GEMV
__global__ __launch_bounds__(64)
void logits_gemv_kernel(const ushort_t* __restrict__ X, int K,
                        const float* __restrict__ w_as, const float* __restrict__ w_ad,
                        float* __restrict__ als, float* __restrict__ ald) {
    int n = blockIdx.x, lane = threadIdx.x;
    float ps[HEADS] = {}, pd[HEADS] = {};
    for (int k0 = lane * 4; k0 < K; k0 += 256) {
        ushort4_t xv = *(const ushort4_t*)&X[(size_t)n * K + k0];
        float x[4] = {bf2f(xv.x), bf2f(xv.y), bf2f(xv.z), bf2f(xv.w)};
        #pragma unroll
        for (int j = 0; j < 4; ++j) {
            #pragma unroll
            for (int h = 0; h < HEADS; ++h) {
                ps[h] += x[j] * w_as[(k0 + j) * 4 + h];
                pd[h] += x[j] * w_ad[(k0 + j) * 4 + h];
            }
        }
    }
    #pragma unroll
    for (int off = 32; off; off >>= 1)
        #pragma unroll
        for (int h = 0; h < HEADS; ++h) {
            ps[h] += __shfl_xor(ps[h], off);
            pd[h] += __shfl_xor(pd[h], off);
        }
    if (lane == 0)
        #pragma unroll
        for (int h = 0; h < HEADS; ++h) {
            als[n * HEADS + h] = ps[h];
            ald[n * HEADS + h] = pd[h];
        }
}

// ---------------------------------------------------------------- per-edge alpha (node-parallel)
__global__ __launch_bounds__(64)
void alpha_kernel(const float* __restrict__ als, const float* __restrict__ ald,
                  const int* __restrict__ row_ptr, const int* __restrict__ csr_src,
                  float* __restrict__ alpha) {
    int d = blockIdx.x, lane = threadIdx.x;
    int beg = row_ptr[d], end = row_ptr[d + 1];
    f32x4 aldd = *(const f32x4*)&ald[d * 4];
    float mx[HEADS] = {-1e30f, -1e30f, -1e30f, -1e30f};
    for (int i = beg + lane; i < end; i += 64) {
        int s = csr_src[i];
        f32x4 av = *(const f32x4*)&als[s * 4];
        #pragma unroll
        for (int h = 0; h < HEADS; ++h)
            mx[h] = fmaxf(mx[h], lrelu(av[h] + aldd[h]));
    }
    #pragma unroll
    for (int off = 32; off; off >>= 1)
        #pragma unroll
        for (int h = 0; h < HEADS; ++h) mx[h] = fmaxf(mx[h], __shfl_xor(mx[h], off));
    float den[HEADS] = {};
    for (int i = beg + lane; i < end; i += 64) {
        int s = csr_src[i];
        f32x4 av = *(const f32x4*)&als[s * 4];
        #pragma unroll
        for (int h = 0; h < HEADS; ++h)
            den[h] += __expf(lrelu(av[h] + aldd[h]) - mx[h]);
    }
    #pragma unroll
    for (int off = 32; off; off >>= 1)
        #pragma unroll
        for (int h = 0; h < HEADS; ++h) den[h] += __shfl_xor(den[h], off);
    float rd[HEADS];
    #pragma unroll
    for (int h = 0; h < HEADS; ++h) rd[h] = 1.f / den[h];
    for (int i = beg + lane; i < end; i += 64) {
        int s = csr_src[i];
        f32x4 av = *(const f32x4*)&als[s * 4];
        f32x4 a;
        #pragma unroll
        for (int h = 0; h < HEADS; ++h)
            a[h] = __expf(lrelu(av[h] + aldd[h]) - mx[h]) * rd[h];
        *(f32x4*)&alpha[(size_t)i * 4] = a;
    }
}

// ---------------------------------------------------------------- agg layer 1 (gather x0b 64 cols -> stacked 320)
__global__ __launch_bounds__(64)
void agg1_kernel(const ushort_t* __restrict__ x0b, const float* __restrict__ alpha,
                 const int* __restrict__ row_ptr, const int* __restrict__ csr_src,
                 ushort_t* __restrict__ aggx) {
    int d = blockIdx.x, lane = threadIdx.x;
    int beg = row_ptr[d], end = row_ptr[d + 1];
    float acc[HEADS] = {};
    for (int i = beg; i < end; ++i) {
        int s = csr_src[i];
        f32x4 a = *(const f32x4*)&alpha[(size_t)i * 4];
        float xv = bf2f(x0b[(size_t)s * KPAD1 + lane]);
        #pragma unroll
        for (int h = 0; h < HEADS; ++h) acc[h] += a[h] * xv;
    }
    #pragma unroll
    for (int h = 0; h < HEADS; ++h)
        aggx[(size_t)d * K1S + h * 64 + lane] = f2bf(acc[h]);
    aggx[(size_t)d * K1S + 256 + lane] = x0b[(size_t)d * KPAD1 + lane];
}

// ---------------------------------------------------------------- agg layer 2 (gather h2 from comb[N,512], fused resid+ReLU)
__global__ __launch_bounds__(64)
void agg2_kernel(const ushort_t* __restrict__ comb, const float* __restrict__ alpha,
                 const int* __restrict__ row_ptr, const int* __restrict__ csr_src,
                 ushort_t* __restrict__ xnext) {
    int d = blockIdx.x, lane = threadIdx.x;
    int beg = row_ptr[d], end = row_ptr[d + 1];
    int hh = lane >> 4;                       // head of cols [lane*4, lane*4+4)
    float a0 = 0, a1 = 0, a2 = 0, a3 = 0;
    for (int i = beg; i < end; ++i) {
        int s = csr_src[i];
        float al = alpha[(size_t)i * 4 + hh];
        ushort4_t xv = *(const ushort4_t*)&comb[(size_t)s * N2S + lane * 4];
        a0 += al * bf2f(xv.x); a1 += al * bf2f(xv.y);
        a2 += al * bf2f(xv.z); a3 += al * bf2f(xv.w);
    }
    ushort4_t rv = *(const ushort4_t*)&comb[(size_t)d * N2S + 256 + lane * 4];
    ushort4_t o;
    o.x = f2bf(fmaxf(a0 + bf2f(rv.x), 0.f));
    o.y = f2bf(fmaxf(a1 + bf2f(rv.y), 0.f));
    o.z = f2bf(fmaxf(a2 + bf2f(rv.z), 0.f));
    o.w = f2bf(fmaxf(a3 + bf2f(rv.w), 0.f));
    *(ushort4_t*)&xnext[(size_t)d * HC1 + lane * 4] = o;
}

// ---------------------------------------------------------------- agg layer 3 (gather x2 256 cols -> stacked 1280)
__global__ __launch_bounds__(64)
void agg3_kernel(const ushort_t* __restrict__ x2b, const float* __restrict__ alpha,
                 const int* __restrict__ row_ptr, const int* __restrict__ csr_src,
                 ushort_t* __restrict__ aggx) {
    int d = blockIdx.x, lane = threadIdx.x;
    int beg = row_ptr[d], end = row_ptr[d + 1];
    float acc[HEADS][4] = {};
    for (int i = beg; i < end; ++i) {
        int s = csr_src[i];
        f32x4 a = *(const f32x4*)&alpha[(size_t)i * 4];
        ushort4_t xv = *(const ushort4_t*)&x2b[(size_t)s * HC1 + lane * 4];
        float x0 = bf2f(xv.x), x1 = bf2f(xv.y), x2 = bf2f(xv.z), x3 = bf2f(xv.w);
        #pragma unroll
        for (int h = 0; h < HEADS; ++h) {
            acc[h][0] += a[h] * x0; acc[h][1] += a[h] * x1;
            acc[h][2] += a[h] * x2; acc[h][3] += a[h] * x3;
        }
    }
    #pragma unroll
    for (int h = 0; h < HEADS; ++h) {
        ushort4_t o;
        o.x = f2bf(acc[h][0]); o.y = f2bf(acc[h][1]);
        o.z = f2bf(acc[h][2]); o.w = f2bf(acc[h][3]);
        *(ushort4_t*)&aggx[(size_t)d * K3S + h * HC1 + lane * 4] = o;
    }
    ushort4_t xd = *(const ushort4_t*)&x2b[(size_t)d * HC1 + lane * 4];
    *(ushort4_t*)&aggx[(size_t)d * K3S + 1024 + lane * 4] = xd;
}

// ---------------------------------------------------------------- launch
extern "C" void kernel_launch(void* const* d_in, const int* in_sizes, int n_in,
                              void* d_out, int out_size, void* d_ws, size_t ws_size,
                              hipStream_t stream) {
    const float* x0   = (const float*)d_in[0];
    const int*   ei   = (const int*)d_in[1];
    const float* W1   = (const float*)d_in[2];
    const float* as1  = (const float*)d_in[3];
    const float* ad1  = (const float*)d_in[4];
    const float* res1 = (const float*)d_in[5];
    const float* b1   = (const float*)d_in[6];
    const float* W2   = (const float*)d_in[7];
    const float* as2  = (const float*)d_in[8];
    const float* ad2  = (const float*)d_in[9];
    const float* res2 = (const float*)d_in[10];
    const float* b2   = (const float*)d_in[11];
    const float* W3   = (const float*)d_in[12];
    const float* as3  = (const float*)d_in[13];
    const float* ad3  = (const float*)d_in[14];
    const float* res3 = (const float*)d_in[15];
    const float* b3   = (const float*)d_in[16];

    char* p = (char*)d_ws;
    auto alloc = [&](size_t bytes) -> void* {
        void* r = (void*)p;
        p += (bytes + 255) & ~(size_t)255;
        return r;
    };
    int*      cnt     = (int*)alloc((size_t)NNODES * 4);
    int*      row_ptr = (int*)alloc((size_t)(NNODES + 1) * 4);
    int*      cursor  = (int*)alloc((size_t)NNODES * 4);
    int*      csr_src = (int*)alloc((size_t)NTOT * 4);
    float*    als     = (float*)alloc((size_t)NNODES * HEADS * 4);
    float*    ald     = (float*)alloc((size_t)NNODES * HEADS * 4);
    float*    alpha   = (float*)alloc((size_t)NTOT * 4 * 4);        // 13.6 MB
    ushort_t* x0b     = (ushort_t*)alloc((size_t)NNODES * KPAD1 * 2);
    ushort_t* x2      = (ushort_t*)alloc((size_t)NNODES * HC1 * 2);
    ushort_t* Bt1     = (ushort_t*)alloc((size_t)HC1 * K1S * 2);
    ushort_t* Bt2     = (ushort_t*)alloc((size_t)N2S * HC1 * 2);
    float*    bias512 = (float*)alloc((size_t)N2S * 4);
    ushort_t* Bt3     = (ushort_t*)alloc((size_t)NC * K3S * 2);
    float*    w_as1   = (float*)alloc((size_t)KPAD1 * 4 * 4);
    float*    w_ad1   = (float*)alloc((size_t)KPAD1 * 4 * 4);
    float*    w_as2   = (float*)alloc((size_t)HC1 * 4 * 4);
    float*    w_ad2   = (float*)alloc((size_t)HC1 * 4 * 4);
    float*    w_as3   = (float*)alloc((size_t)HC1 * 4 * 4);
    float*    w_ad3   = (float*)alloc((size_t)HC1 * 4 * 4);
    // aliased region: layer-1/2 temporaries, reused as aggx3 [N,1280] bf16 (128 MB)
    char*     big     = (char*)alloc((size_t)NNODES * K3S * 2);
    ushort_t* aggx1   = (ushort_t*)big;                                       // [N,320]
    ushort_t* x1      = (ushort_t*)(big + (size_t)NNODES * K1S * 2);          // [N,256]
    ushort_t* comb    = (ushort_t*)(big + (size_t)NNODES * (K1S + HC1) * 2);  // [N,512]
    ushort_t* aggx3   = (ushort_t*)big;                                       // [N,1280] (layer 3)

    hipMemsetAsync(cnt, 0, (size_t)NNODES * 4, stream);

    int tb = 256;
    count_kernel<<<(NTOT + tb - 1) / tb, tb, 0, stream>>>(ei, cnt);
    scan_kernel<<<1, SCAN_T, 0, stream>>>(cnt, row_ptr, cursor, NNODES);
    scatter_kernel<<<(NTOT + tb - 1) / tb, tb, 0, stream>>>(ei, cursor, csr_src);

    // weight prep
    conv_pad_kernel<<<(NNODES * KPAD1 + tb - 1) / tb, tb, 0, stream>>>(x0, x0b, NNODES, F_IN, KPAD1);
    build_bt1_kernel<<<(HC1 * K1S + tb - 1) / tb, tb, 0, stream>>>(W1, res1, Bt1);
    build_bt2_kernel<<<(N2S * HC1 + tb - 1) / tb, tb, 0, stream>>>(W2, res2, Bt2);
    build_bias2_kernel<<<(N2S + tb - 1) / tb, tb, 0, stream>>>(b2, bias512);
    build_bt3_kernel<<<(NC * K3S + tb - 1) / tb, tb, 0, stream>>>(W3, res3, Bt3);
    build_w_kernel<<<(KPAD1 * 4 + tb - 1) / tb, tb, 0, stream>>>(W1, as1, w_as1, F_IN, KPAD1, C1);
    build_w_kernel<<<(KPAD1 * 4 + tb - 1) / tb, tb, 0, stream>>>(W1, ad1, w_ad1, F_IN, KPAD1, C1);
    build_w_kernel<<<(HC1 * 4 + tb - 1) / tb, tb, 0, stream>>>(W2, as2, w_as2, HC1, HC1, C1);
    build_w_kernel<<<(HC1 * 4 + tb - 1) / tb, tb, 0, stream>>>(W2, ad2, w_ad2, HC1, HC1, C1);
    build_w_kernel<<<(HC1 * 4 + tb - 1) / tb, tb, 0, stream>>>(W3, as3, w_as3, HC1, HC1, NC);
    build_w_kernel<<<(HC1 * 4 + tb - 1) / tb, tb, 0, stream>>>(W3, ad3, w_ad3, HC1, HC1, NC);

    auto gemm = [&](const ushort_t* A, const ushort_t* Bt, const float* bias,
                    float* Cf, ushort_t* Cb, int M, int Nn, int K, int relu) {
        dim3 g((Nn + BN - 1) / BN, (M + BM - 1) / BM);
        gemm_mfma_kernel<<<g, 256, 0, stream>>>(A, Bt, bias, Cf, Cb, M, Nn, K, relu);
    };

    // ---- layer 1 (aggregate-then-transform)
    logits_gemv_kernel<<<NNODES, 64, 0, stream>>>(x0b, KPAD1, w_as1, w_ad1, als, ald);
    alpha_kernel<<<NNODES, 64, 0, stream>>>(als, ald, row_ptr, csr_src, alpha);
    agg1_kernel<<<NNODES, 64, 0, stream>>>(x0b, alpha, row_ptr, csr_src, aggx1);
    gemm(aggx1, Bt1, b1, nullptr, x1, NNODES, HC1, K1S, 1);

    // ---- layer 2 (single stacked GEMM: [h2 | resid] bf16)
    gemm(x1, Bt2, bias512, nullptr, comb, NNODES, N2S, HC1, 0);
    logits_gemv_kernel<<<NNODES, 64, 0, stream>>>(x1, HC1, w_as2, w_ad2, als, ald);
    alpha_kernel<<<NNODES, 64, 0, stream>>>(als, ald, row_ptr, csr_src, alpha);
    agg2_kernel<<<NNODES, 64, 0, stream>>>(comb, alpha, row_ptr, csr_src, x2);

    // ---- layer 3 (aggregate-then-transform)
    logits_gemv_kernel<<<NNODES, 64, 0, stream>>>(x2, HC1, w_as3, w_ad3, als, ald);
    alpha_kernel<<<NNODES, 64, 0, stream>>>(als, ald, row_ptr, csr_src, alpha);
    agg3_kernel<<<NNODES, 64, 0, stream>>>(x2, alpha, row_ptr, csr_src, aggx3);
    gemm(aggx3, Bt3, b3, (float*)d_out, nullptr, NNODES, NC, K3S, 0);
}

// Round 6
// 844.709 us; speedup vs baseline: 2.0667x; 1.1275x over previous
//
#include <hip/hip_runtime.h>

#define NNODES 50000
#define NEDGES 800000
#define NTOT   (NEDGES + NNODES)   // edges + self loops
#define F_IN   50
#define KPAD1  64                  // F_IN padded to 64
#define HEADS  4
#define C1     64
#define HC1    256                 // HEADS*C1
#define NC     121
#define K1S    320                 // stacked K layer1: 4*64 + 64
#define K3S    1280                // stacked K layer3: 4*256 + 256
#define N2S    512                 // stacked N layer2: 256 (W2) + 256 (res2)

typedef unsigned short ushort_t;
typedef __attribute__((ext_vector_type(4))) unsigned short ushort4_t;
typedef __attribute__((ext_vector_type(8))) unsigned short ushort8;
typedef __attribute__((ext_vector_type(8))) __bf16 bf16x8;
typedef __attribute__((ext_vector_type(4))) float f32x4;

__device__ __forceinline__ ushort_t f2bf(float f) {
    union { float f; unsigned int u; } v; v.f = f;
    unsigned int u = v.u;
    return (ushort_t)((u + 0x7fffu + ((u >> 16) & 1u)) >> 16);   // RNE
}
__device__ __forceinline__ float bf2f(ushort_t s) {
    union { unsigned int u; float f; } v; v.u = ((unsigned int)s) << 16;
    return v.f;
}
__device__ __forceinline__ float lrelu(float x) { return x > 0.f ? x : 0.2f * x; }

// ---------------------------------------------------------------- CSR build
__global__ void count_kernel(const int* __restrict__ ei, int* __restrict__ cnt) {
    int i = blockIdx.x * blockDim.x + threadIdx.x;
    if (i >= NTOT) return;
    int d = (i < NEDGES) ? ei[NEDGES + i] : (i - NEDGES);
    if ((unsigned)d >= NNODES) d = 0;
    atomicAdd(&cnt[d], 1);
}

// hierarchical exclusive scan of cnt[0..n) -> row_ptr/cursor
#define SCB 256
__global__ __launch_bounds__(SCB)
void scan1_kernel(const int* __restrict__ cnt, int* __restrict__ incl,
                  int* __restrict__ bsums, int n) {
    __shared__ int buf[SCB];
    int b = blockIdx.x, tid = threadIdx.x;
    int i = b * SCB + tid;
    int v = (i < n) ? cnt[i] : 0;
    buf[tid] = v;
    __syncthreads();
    for (int off = 1; off < SCB; off <<= 1) {
        int t = (tid >= off) ? buf[tid - off] : 0;
        __syncthreads();
        buf[tid] += t;
        __syncthreads();
    }
    if (i < n) incl[i] = buf[tid];
    if (tid == SCB - 1) bsums[b] = buf[tid];
}

__global__ __launch_bounds__(SCB)
void scan2_kernel(int* __restrict__ bsums, int nb) {
    __shared__ int buf[SCB];
    int tid = threadIdx.x;
    int v = (tid < nb) ? bsums[tid] : 0;
    buf[tid] = v;
    __syncthreads();
    for (int off = 1; off < SCB; off <<= 1) {
        int t = (tid >= off) ? buf[tid - off] : 0;
        __syncthreads();
        buf[tid] += t;
        __syncthreads();
    }
    if (tid < nb) bsums[tid] = buf[tid] - v;   // exclusive
}

__global__ __launch_bounds__(SCB)
void scan3_kernel(const int* __restrict__ cnt, const int* __restrict__ incl,
                  const int* __restrict__ bsums, int* __restrict__ row_ptr,
                  int* __restrict__ cursor, int n) {
    int b = blockIdx.x, tid = threadIdx.x;
    int i = b * SCB + tid;
    if (i >= n) return;
    int e = bsums[b] + incl[i] - cnt[i];
    row_ptr[i] = e; cursor[i] = e;
    if (i == n - 1) row_ptr[n] = NTOT;         // total is statically NTOT
}

__global__ void scatter_kernel(const int* __restrict__ ei, int* __restrict__ cursor,
                               int* __restrict__ csr_src) {
    int i = blockIdx.x * blockDim.x + threadIdx.x;
    if (i >= NTOT) return;
    int s, d;
    if (i < NEDGES) { s = ei[i]; d = ei[NEDGES + i]; }
    else            { s = d = i - NEDGES; }
    if ((unsigned)d >= NNODES) d = 0;
    if ((unsigned)s >= NNODES) s = 0;
    int pos = atomicAdd(&cursor[d], 1);
    csr_src[pos] = s;
}

// ---------------------------------------------------------------- converts / builders
__global__ void conv_pad_kernel(const float* __restrict__ in, ushort_t* __restrict__ out,
                                int M, int Kin, int Kout) {
    int i = blockIdx.x * blockDim.x + threadIdx.x;
    if (i >= M * Kout) return;
    int m = i / Kout, k = i - m * Kout;
    out[i] = (k < Kin) ? f2bf(in[(size_t)m * Kin + k]) : (ushort_t)0;
}

// w[k,h] = sum_c W[k, h*C+c] * a[h,c]; [Kpad,4] f32
__global__ void build_w_kernel(const float* __restrict__ W, const float* __restrict__ a,
                               float* __restrict__ w, int Kin, int Kpad, int C) {
    int i = blockIdx.x * blockDim.x + threadIdx.x;
    if (i >= Kpad * 4) return;
    int k = i >> 2, h = i & 3;
    float s = 0.f;
    if (k < Kin)
        for (int c = 0; c < C; ++c) s += W[(size_t)k * (4 * C) + h * C + c] * a[h * C + c];
    w[i] = s;
}

// Bt1 [256, 320]: (block-diag W1 per head | res1)^T
__global__ void build_bt1_kernel(const float* __restrict__ W1, const float* __restrict__ res1,
                                 ushort_t* __restrict__ Bt1) {
    int i = blockIdx.x * blockDim.x + threadIdx.x;
    if (i >= HC1 * K1S) return;
    int c = i / K1S, kk = i - c * K1S;
    float v = 0.f;
    if (kk < 256) {
        int h = kk >> 6, k = kk & 63;
        if (k < F_IN && (c >> 6) == h) v = W1[(size_t)k * HC1 + c];
    } else {
        int k = kk - 256;
        if (k < F_IN) v = res1[(size_t)k * HC1 + c];
    }
    Bt1[i] = f2bf(v);
}

// Bt2 [512, 256]: columns 0..255 = W2, 256..511 = res2, transposed
__global__ void build_bt2_kernel(const float* __restrict__ W2, const float* __restrict__ res2,
                                 ushort_t* __restrict__ Bt2) {
    int i = blockIdx.x * blockDim.x + threadIdx.x;
    if (i >= N2S * HC1) return;
    int c = i / HC1, k = i - c * HC1;
    float v = (c < HC1) ? W2[(size_t)k * HC1 + c] : res2[(size_t)k * HC1 + (c - HC1)];
    Bt2[i] = f2bf(v);
}

__global__ void build_bias2_kernel(const float* __restrict__ b2, float* __restrict__ bias512) {
    int i = blockIdx.x * blockDim.x + threadIdx.x;
    if (i >= N2S) return;
    bias512[i] = (i < HC1) ? 0.f : b2[i - HC1];
}

// Bt3 [121, 1280]: (0.25*W3 per head stacked | res3)^T
__global__ void build_bt3_kernel(const float* __restrict__ W3, const float* __restrict__ res3,
                                 ushort_t* __restrict__ Bt3) {
    int i = blockIdx.x * blockDim.x + threadIdx.x;
    if (i >= NC * K3S) return;
    int c = i / K3S, kk = i - c * K3S;
    float v;
    if (kk < 1024) {
        int h = kk >> 8, k = kk & 255;
        v = 0.25f * W3[(size_t)k * (HEADS * NC) + h * NC + c];
    } else {
        int k = kk - 1024;
        v = res3[(size_t)k * NC + c];
    }
    Bt3[i] = f2bf(v);
}

// ---------------------------------------------------------------- MFMA GEMM
#define BM 128
#define BN 128
#define BK 64
#define LDP (BK + 8)

__global__ __launch_bounds__(256)
void gemm_mfma_kernel(const ushort_t* __restrict__ A, const ushort_t* __restrict__ Bt,
                      const float* __restrict__ bias,
                      float* __restrict__ Cf, ushort_t* __restrict__ Cb,
                      int M, int N, int K, int relu) {
    __shared__ ushort_t As[BM * LDP];
    __shared__ ushort_t Bs[BN * LDP];
    int tid = threadIdx.x;
    int lane = tid & 63;
    int wid = tid >> 6;
    int wm = (wid & 1) * 64, wn = (wid >> 1) * 64;
    int l15 = lane & 15;
    int q8 = (lane >> 4) * 8;
    int m0 = blockIdx.y * BM, n0 = blockIdx.x * BN;

    f32x4 acc[4][4] = {};

    for (int k0 = 0; k0 < K; k0 += BK) {
        #pragma unroll
        for (int it = 0; it < 4; ++it) {
            int c = tid + it * 256;
            int row = c >> 3, c8 = c & 7;
            ushort8 va = (ushort8)0;
            int gm = m0 + row;
            if (gm < M) va = *(const ushort8*)&A[(size_t)gm * K + k0 + c8 * 8];
            *(ushort8*)&As[row * LDP + c8 * 8] = va;
            ushort8 vb = (ushort8)0;
            int gn = n0 + row;
            if (gn < N) vb = *(const ushort8*)&Bt[(size_t)gn * K + k0 + c8 * 8];
            *(ushort8*)&Bs[row * LDP + c8 * 8] = vb;
        }
        __syncthreads();
        #pragma unroll
        for (int kk = 0; kk < BK; kk += 32) {
            bf16x8 af[4], bfr[4];
            #pragma unroll
            for (int mi = 0; mi < 4; ++mi)
                af[mi] = *(const bf16x8*)&As[(wm + mi * 16 + l15) * LDP + kk + q8];
            #pragma unroll
            for (int ni = 0; ni < 4; ++ni)
                bfr[ni] = *(const bf16x8*)&Bs[(wn + ni * 16 + l15) * LDP + kk + q8];
            #pragma unroll
            for (int mi = 0; mi < 4; ++mi)
                #pragma unroll
                for (int ni = 0; ni < 4; ++ni)
                    acc[mi][ni] = __builtin_amdgcn_mfma_f32_16x16x32_bf16(
                        af[mi], bfr[ni], acc[mi][ni], 0, 0, 0);
        }
        __syncthreads();
    }

    #pragma unroll
    for (int mi = 0; mi < 4; ++mi) {
        int mbase = m0 + wm + mi * 16 + (lane >> 4) * 4;
        #pragma unroll
        for (int ni = 0; ni < 4; ++ni) {
            int ncol = n0 + wn + ni * 16 + l15;
            if (ncol >= N) continue;
            float bv = bias ? bias[ncol] : 0.f;
            #pragma unroll
            for (int r = 0; r < 4; ++r) {
                int m = mbase + r;
                if (m >= M) continue;
                float v = acc[mi][ni][r] + bv;
                if (relu) v = fmaxf(v, 0.f);
                if (Cf) Cf[(size_t)m * N + ncol] = v;
                else    Cb[(size_t)m * N + ncol] = f2bf(v);
            }
        }
    }
}

// ---------------------------------------------------------------- logits GEMV
__global__ __launch_bounds__(64)
void logits_gemv_kernel(const ushort_t* __restrict__ X, int K,
                        const float* __restrict__ w_as, const float* __restrict__ w_ad,
                        float* __restrict__ als, float* __restrict__ ald) {
    int n = blockIdx.x, lane = threadIdx.x;
    float ps[HEADS] = {}, pd[HEADS] = {};
    for (int k0 = lane * 4; k0 < K; k0 += 256) {
        ushort4_t xv = *(const ushort4_t*)&X[(size_t)n * K + k0];
        float x[4] = {bf2f(xv.x), bf2f(xv.y), bf2f(xv.z), bf2f(xv.w)};
        #pragma unroll
        for (int j = 0; j < 4; ++j) {
            #pragma unroll
            for (int h = 0; h < HEADS; ++h) {
                ps[h] += x[j] * w_as[(k0 + j) * 4 + h];
                pd[h] += x[j] * w_ad[(k0 + j) * 4 + h];
            }
        }
    }
    #pragma unroll
    for (int off = 32; off; off >>= 1)
        #pragma unroll
        for (int h = 0; h < HEADS; ++h) {
            ps[h] += __shfl_xor(ps[h], off);
            pd[h] += __shfl_xor(pd[h], off);
        }
    if (lane == 0)
        #pragma unroll
        for (int h = 0; h < HEADS; ++h) {
            als[n * HEADS + h] = ps[h];
            ald[n * HEADS + h] = pd[h];
        }
}

// ---------------------------------------------------------------- per-edge alpha (node-parallel)
__global__ __launch_bounds__(64)
void alpha_kernel(const float* __restrict__ als, const float* __restrict__ ald,
                  const int* __restrict__ row_ptr, const int* __restrict__ csr_src,
                  float* __restrict__ alpha) {
    int d = blockIdx.x, lane = threadIdx.x;
    int beg = row_ptr[d], end = row_ptr[d + 1];
    f32x4 aldd = *(const f32x4*)&ald[d * 4];
    float mx[HEADS] = {-1e30f, -1e30f, -1e30f, -1e30f};
    for (int i = beg + lane; i < end; i += 64) {
        int s = csr_src[i];
        f32x4 av = *(const f32x4*)&als[s * 4];
        #pragma unroll
        for (int h = 0; h < HEADS; ++h)
            mx[h] = fmaxf(mx[h], lrelu(av[h] + aldd[h]));
    }
    #pragma unroll
    for (int off = 32; off; off >>= 1)
        #pragma unroll
        for (int h = 0; h < HEADS; ++h) mx[h] = fmaxf(mx[h], __shfl_xor(mx[h], off));
    float den[HEADS] = {};
    for (int i = beg + lane; i < end; i += 64) {
        int s = csr_src[i];
        f32x4 av = *(const f32x4*)&als[s * 4];
        #pragma unroll
        for (int h = 0; h < HEADS; ++h)
            den[h] += __expf(lrelu(av[h] + aldd[h]) - mx[h]);
    }
    #pragma unroll
    for (int off = 32; off; off >>= 1)
        #pragma unroll
        for (int h = 0; h < HEADS; ++h) den[h] += __shfl_xor(den[h], off);
    float rd[HEADS];
    #pragma unroll
    for (int h = 0; h < HEADS; ++h) rd[h] = 1.f / den[h];
    for (int i = beg + lane; i < end; i += 64) {
        int s = csr_src[i];
        f32x4 av = *(const f32x4*)&als[s * 4];
        f32x4 a;
        #pragma unroll
        for (int h = 0; h < HEADS; ++h)
            a[h] = __expf(lrelu(av[h] + aldd[h]) - mx[h]) * rd[h];
        *(f32x4*)&alpha[(size_t)i * 4] = a;
    }
}

// ---------------------------------------------------------------- agg layer 1 (gather x0b 64 cols -> stacked 320)
__global__ __launch_bounds__(64)
void agg1_kernel(const ushort_t* __restrict__ x0b, const float* __restrict__ alpha,
                 const int* __restrict__ row_ptr, const int* __restrict__ csr_src,
                 ushort_t* __restrict__ aggx) {
    int d = blockIdx.x, lane = threadIdx.x;
    int beg = row_ptr[d], end = row_ptr[d + 1];
    float acc[HEADS] = {};
    for (int i = beg; i < end; ++i) {
        int s = csr_src[i];
        f32x4 a = *(const f32x4*)&alpha[(size_t)i * 4];
        float xv = bf2f(x0b[(size_t)s * KPAD1 + lane]);
        #pragma unroll
        for (int h = 0; h < HEADS; ++h) acc[h] += a[h] * xv;
    }
    #pragma unroll
    for (int h = 0; h < HEADS; ++h)
        aggx[(size_t)d * K1S + h * 64 + lane] = f2bf(acc[h]);
    aggx[(size_t)d * K1S + 256 + lane] = x0b[(size_t)d * KPAD1 + lane];
}

// ---------------------------------------------------------------- agg layer 2 (gather h2 from comb[N,512], fused resid+ReLU)
__global__ __launch_bounds__(64)
void agg2_kernel(const ushort_t* __restrict__ comb, const float* __restrict__ alpha,
                 const int* __restrict__ row_ptr, const int* __restrict__ csr_src,
                 ushort_t* __restrict__ xnext) {
    int d = blockIdx.x, lane = threadIdx.x;
    int beg = row_ptr[d], end = row_ptr[d + 1];
    int hh = lane >> 4;                       // head of cols [lane*4, lane*4+4)
    float a0 = 0, a1 = 0, a2 = 0, a3 = 0;
    for (int i = beg; i < end; ++i) {
        int s = csr_src[i];
        float al = alpha[(size_t)i * 4 + hh];
        ushort4_t xv = *(const ushort4_t*)&comb[(size_t)s * N2S + lane * 4];
        a0 += al * bf2f(xv.x); a1 += al * bf2f(xv.y);
        a2 += al * bf2f(xv.z); a3 += al * bf2f(xv.w);
    }
    ushort4_t rv = *(const ushort4_t*)&comb[(size_t)d * N2S + 256 + lane * 4];
    ushort4_t o;
    o.x = f2bf(fmaxf(a0 + bf2f(rv.x), 0.f));
    o.y = f2bf(fmaxf(a1 + bf2f(rv.y), 0.f));
    o.z = f2bf(fmaxf(a2 + bf2f(rv.z), 0.f));
    o.w = f2bf(fmaxf(a3 + bf2f(rv.w), 0.f));
    *(ushort4_t*)&xnext[(size_t)d * HC1 + lane * 4] = o;
}

// ---------------------------------------------------------------- agg layer 3 (gather x2 256 cols -> stacked 1280)
__global__ __launch_bounds__(64)
void agg3_kernel(const ushort_t* __restrict__ x2b, const float* __restrict__ alpha,
                 const int* __restrict__ row_ptr, const int* __restrict__ csr_src,
                 ushort_t* __restrict__ aggx) {
    int d = blockIdx.x, lane = threadIdx.x;
    int beg = row_ptr[d], end = row_ptr[d + 1];
    float acc[HEADS][4] = {};
    for (int i = beg; i < end; ++i) {
        int s = csr_src[i];
        f32x4 a = *(const f32x4*)&alpha[(size_t)i * 4];
        ushort4_t xv = *(const ushort4_t*)&x2b[(size_t)s * HC1 + lane * 4];
        float x0 = bf2f(xv.x), x1 = bf2f(xv.y), x2 = bf2f(xv.z), x3 = bf2f(xv.w);
        #pragma unroll
        for (int h = 0; h < HEADS; ++h) {
            acc[h][0] += a[h] * x0; acc[h][1] += a[h] * x1;
            acc[h][2] += a[h] * x2; acc[h][3] += a[h] * x3;
        }
    }
    #pragma unroll
    for (int h = 0; h < HEADS; ++h) {
        ushort4_t o;
        o.x = f2bf(acc[h][0]); o.y = f2bf(acc[h][1]);
        o.z = f2bf(acc[h][2]); o.w = f2bf(acc[h][3]);
        *(ushort4_t*)&aggx[(size_t)d * K3S + h * HC1 + lane * 4] = o;
    }
    ushort4_t xd = *(const ushort4_t*)&x2b[(size_t)d * HC1 + lane * 4];
    *(ushort4_t*)&aggx[(size_t)d * K3S + 1024 + lane * 4] = xd;
}

// ---------------------------------------------------------------- launch
extern "C" void kernel_launch(void* const* d_in, const int* in_sizes, int n_in,
                              void* d_out, int out_size, void* d_ws, size_t ws_size,
                              hipStream_t stream) {
    const float* x0   = (const float*)d_in[0];
    const int*   ei   = (const int*)d_in[1];
    const float* W1   = (const float*)d_in[2];
    const float* as1  = (const float*)d_in[3];
    const float* ad1  = (const float*)d_in[4];
    const float* res1 = (const float*)d_in[5];
    const float* b1   = (const float*)d_in[6];
    const float* W2   = (const float*)d_in[7];
    const float* as2  = (const float*)d_in[8];
    const float* ad2  = (const float*)d_in[9];
    const float* res2 = (const float*)d_in[10];
    const float* b2   = (const float*)d_in[11];
    const float* W3   = (const float*)d_in[12];
    const float* as3  = (const float*)d_in[13];
    const float* ad3  = (const float*)d_in[14];
    const float* res3 = (const float*)d_in[15];
    const float* b3   = (const float*)d_in[16];

    char* p = (char*)d_ws;
    auto alloc = [&](size_t bytes) -> void* {
        void* r = (void*)p;
        p += (bytes + 255) & ~(size_t)255;
        return r;
    };
    int*      cnt     = (int*)alloc((size_t)NNODES * 4);
    int*      incl    = (int*)alloc((size_t)NNODES * 4);
    int*      bsums   = (int*)alloc((size_t)SCB * 4);
    int*      row_ptr = (int*)alloc((size_t)(NNODES + 1) * 4);
    int*      cursor  = (int*)alloc((size_t)NNODES * 4);
    int*      csr_src = (int*)alloc((size_t)NTOT * 4);
    float*    als     = (float*)alloc((size_t)NNODES * HEADS * 4);
    float*    ald     = (float*)alloc((size_t)NNODES * HEADS * 4);
    float*    alpha   = (float*)alloc((size_t)NTOT * 4 * 4);        // 13.6 MB
    ushort_t* x0b     = (ushort_t*)alloc((size_t)NNODES * KPAD1 * 2);
    ushort_t* x2      = (ushort_t*)alloc((size_t)NNODES * HC1 * 2);
    ushort_t* Bt1     = (ushort_t*)alloc((size_t)HC1 * K1S * 2);
    ushort_t* Bt2     = (ushort_t*)alloc((size_t)N2S * HC1 * 2);
    float*    bias512 = (float*)alloc((size_t)N2S * 4);
    ushort_t* Bt3     = (ushort_t*)alloc((size_t)NC * K3S * 2);
    float*    w_as1   = (float*)alloc((size_t)KPAD1 * 4 * 4);
    float*    w_ad1   = (float*)alloc((size_t)KPAD1 * 4 * 4);
    float*    w_as2   = (float*)alloc((size_t)HC1 * 4 * 4);
    float*    w_ad2   = (float*)alloc((size_t)HC1 * 4 * 4);
    float*    w_as3   = (float*)alloc((size_t)HC1 * 4 * 4);
    float*    w_ad3   = (float*)alloc((size_t)HC1 * 4 * 4);
    // aliased region: layer-1/2 temporaries, reused as aggx3 [N,1280] bf16 (128 MB)
    char*     big     = (char*)alloc((size_t)NNODES * K3S * 2);
    ushort_t* aggx1   = (ushort_t*)big;                                       // [N,320]
    ushort_t* x1      = (ushort_t*)(big + (size_t)NNODES * K1S * 2);          // [N,256]
    ushort_t* comb    = (ushort_t*)(big + (size_t)NNODES * (K1S + HC1) * 2);  // [N,512]
    ushort_t* aggx3   = (ushort_t*)big;                                       // [N,1280] (layer 3)

    hipMemsetAsync(cnt, 0, (size_t)NNODES * 4, stream);

    int tb = 256;
    int nscan = (NNODES + SCB - 1) / SCB;     // 196 blocks
    count_kernel<<<(NTOT + tb - 1) / tb, tb, 0, stream>>>(ei, cnt);
    scan1_kernel<<<nscan, SCB, 0, stream>>>(cnt, incl, bsums, NNODES);
    scan2_kernel<<<1, SCB, 0, stream>>>(bsums, nscan);
    scan3_kernel<<<nscan, SCB, 0, stream>>>(cnt, incl, bsums, row_ptr, cursor, NNODES);
    scatter_kernel<<<(NTOT + tb - 1) / tb, tb, 0, stream>>>(ei, cursor, csr_src);

    // weight prep
    conv_pad_kernel<<<(NNODES * KPAD1 + tb - 1) / tb, tb, 0, stream>>>(x0, x0b, NNODES, F_IN, KPAD1);
    build_bt1_kernel<<<(HC1 * K1S + tb - 1) / tb, tb, 0, stream>>>(W1, res1, Bt1);
    build_bt2_kernel<<<(N2S * HC1 + tb - 1) / tb, tb, 0, stream>>>(W2, res2, Bt2);
    build_bias2_kernel<<<(N2S + tb - 1) / tb, tb, 0, stream>>>(b2, bias512);
    build_bt3_kernel<<<(NC * K3S + tb - 1) / tb, tb, 0, stream>>>(W3, res3, Bt3);
    build_w_kernel<<<(KPAD1 * 4 + tb - 1) / tb, tb, 0, stream>>>(W1, as1, w_as1, F_IN, KPAD1, C1);
    build_w_kernel<<<(KPAD1 * 4 + tb - 1) / tb, tb, 0, stream>>>(W1, ad1, w_ad1, F_IN, KPAD1, C1);
    build_w_kernel<<<(HC1 * 4 + tb - 1) / tb, tb, 0, stream>>>(W2, as2, w_as2, HC1, HC1, C1);
    build_w_kernel<<<(HC1 * 4 + tb - 1) / tb, tb, 0, stream>>>(W2, ad2, w_ad2, HC1, HC1, C1);
    build_w_kernel<<<(HC1 * 4 + tb - 1) / tb, tb, 0, stream>>>(W3, as3, w_as3, HC1, HC1, NC);
    build_w_kernel<<<(HC1 * 4 + tb - 1) / tb, tb, 0, stream>>>(W3, ad3, w_ad3, HC1, HC1, NC);

    auto gemm = [&](const ushort_t* A, const ushort_t* Bt, const float* bias,
                    float* Cf, ushort_t* Cb, int M, int Nn, int K, int relu) {
        dim3 g((Nn + BN - 1) / BN, (M + BM - 1) / BM);
        gemm_mfma_kernel<<<g, 256, 0, stream>>>(A, Bt, bias, Cf, Cb, M, Nn, K, relu);
    };

    // ---- layer 1 (aggregate-then-transform)
    logits_gemv_kernel<<<NNODES, 64, 0, stream>>>(x0b, KPAD1, w_as1, w_ad1, als, ald);
    alpha_kernel<<<NNODES, 64, 0, stream>>>(als, ald, row_ptr, csr_src, alpha);
    agg1_kernel<<<NNODES, 64, 0, stream>>>(x0b, alpha, row_ptr, csr_src, aggx1);
    gemm(aggx1, Bt1, b1, nullptr, x1, NNODES, HC1, K1S, 1);

    // ---- layer 2 (single stacked GEMM: [h2 | resid] bf16)
    gemm(x1, Bt2, bias512, nullptr, comb, NNODES, N2S, HC1, 0);
    logits_gemv_kernel<<<NNODES, 64, 0, stream>>>(x1, HC1, w_as2, w_ad2, als, ald);
    alpha_kernel<<<NNODES, 64, 0, stream>>>(als, ald, row_ptr, csr_src, alpha);
    agg2_kernel<<<NNODES, 64, 0, stream>>>(comb, alpha, row_ptr, csr_src, x2);

    // ---- layer 3 (aggregate-then-transform)
    logits_gemv_kernel<<<NNODES, 64, 0, stream>>>(x2, HC1, w_as3, w_ad3, als, ald);
    alpha_kernel<<<NNODES, 64, 0, stream>>>(als, ald, row_ptr, csr_src, alpha);
    agg3_kernel<<<NNODES, 64, 0, stream>>>(x2, alpha, row_ptr, csr_src, aggx3);
    gemm(aggx3, Bt3, b3, (float*)d_out, nullptr, NNODES, NC, K3S, 0);
}

// Round 7
// 742.856 us; speedup vs baseline: 2.3500x; 1.1371x over previous
//
#include <hip/hip_runtime.h>

#define NNODES 50000
#define NEDGES 800000
#define NTOT   (NEDGES + NNODES)   // edges + self loops
#define F_IN   50
#define KPAD1  64                  // F_IN padded to 64
#define HEADS  4
#define C1     64
#define HC1    256                 // HEADS*C1
#define NC     121
#define K1S    320                 // layer1 GEMM K: 256 (agg) + 64 (x0)
#define K3S    1280                // layer3 GEMM K: 1024 (agg) + 256 (x2)
#define N2S    512                 // layer2 GEMM N: 256 (W2) + 256 (res2)

typedef unsigned short ushort_t;
typedef __attribute__((ext_vector_type(4))) unsigned short ushort4_t;
typedef __attribute__((ext_vector_type(8))) unsigned short ushort8;
typedef __attribute__((ext_vector_type(8))) __bf16 bf16x8;
typedef __attribute__((ext_vector_type(4))) float f32x4;

__device__ __forceinline__ ushort_t f2bf(float f) {
    union { float f; unsigned int u; } v; v.f = f;
    unsigned int u = v.u;
    return (ushort_t)((u + 0x7fffu + ((u >> 16) & 1u)) >> 16);   // RNE
}
__device__ __forceinline__ float bf2f(ushort_t s) {
    union { unsigned int u; float f; } v; v.u = ((unsigned int)s) << 16;
    return v.f;
}
__device__ __forceinline__ float lrelu(float x) { return x > 0.f ? x : 0.2f * x; }

// ---------------------------------------------------------------- CSR build
__global__ void count_kernel(const int* __restrict__ ei, int* __restrict__ cnt) {
    int i = blockIdx.x * blockDim.x + threadIdx.x;
    if (i >= NTOT) return;
    int d = (i < NEDGES) ? ei[NEDGES + i] : (i - NEDGES);
    if ((unsigned)d >= NNODES) d = 0;
    atomicAdd(&cnt[d], 1);
}

#define SCB 256
__global__ __launch_bounds__(SCB)
void scan1_kernel(const int* __restrict__ cnt, int* __restrict__ incl,
                  int* __restrict__ bsums, int n) {
    __shared__ int buf[SCB];
    int b = blockIdx.x, tid = threadIdx.x;
    int i = b * SCB + tid;
    int v = (i < n) ? cnt[i] : 0;
    buf[tid] = v;
    __syncthreads();
    for (int off = 1; off < SCB; off <<= 1) {
        int t = (tid >= off) ? buf[tid - off] : 0;
        __syncthreads();
        buf[tid] += t;
        __syncthreads();
    }
    if (i < n) incl[i] = buf[tid];
    if (tid == SCB - 1) bsums[b] = buf[tid];
}

__global__ __launch_bounds__(SCB)
void scan2_kernel(int* __restrict__ bsums, int nb) {
    __shared__ int buf[SCB];
    int tid = threadIdx.x;
    int v = (tid < nb) ? bsums[tid] : 0;
    buf[tid] = v;
    __syncthreads();
    for (int off = 1; off < SCB; off <<= 1) {
        int t = (tid >= off) ? buf[tid - off] : 0;
        __syncthreads();
        buf[tid] += t;
        __syncthreads();
    }
    if (tid < nb) bsums[tid] = buf[tid] - v;   // exclusive
}

__global__ __launch_bounds__(SCB)
void scan3_kernel(const int* __restrict__ cnt, const int* __restrict__ incl,
                  const int* __restrict__ bsums, int* __restrict__ row_ptr,
                  int* __restrict__ cursor, int n) {
    int b = blockIdx.x, tid = threadIdx.x;
    int i = b * SCB + tid;
    if (i >= n) return;
    int e = bsums[b] + incl[i] - cnt[i];
    row_ptr[i] = e; cursor[i] = e;
    if (i == n - 1) row_ptr[n] = NTOT;
}

__global__ void scatter_kernel(const int* __restrict__ ei, int* __restrict__ cursor,
                               int* __restrict__ csr_src) {
    int i = blockIdx.x * blockDim.x + threadIdx.x;
    if (i >= NTOT) return;
    int s, d;
    if (i < NEDGES) { s = ei[i]; d = ei[NEDGES + i]; }
    else            { s = d = i - NEDGES; }
    if ((unsigned)d >= NNODES) d = 0;
    if ((unsigned)s >= NNODES) s = 0;
    int pos = atomicAdd(&cursor[d], 1);
    csr_src[pos] = s;
}

// ---------------------------------------------------------------- converts / builders
__global__ void conv_pad_kernel(const float* __restrict__ in, ushort_t* __restrict__ out,
                                int M, int Kin, int Kout) {
    int i = blockIdx.x * blockDim.x + threadIdx.x;
    if (i >= M * Kout) return;
    int m = i / Kout, k = i - m * Kout;
    out[i] = (k < Kin) ? f2bf(in[(size_t)m * Kin + k]) : (ushort_t)0;
}

// w[k,h] = sum_c W[k, h*C+c] * a[h,c]; [Kpad,4] f32
__global__ void build_w_kernel(const float* __restrict__ W, const float* __restrict__ a,
                               float* __restrict__ w, int Kin, int Kpad, int C) {
    int i = blockIdx.x * blockDim.x + threadIdx.x;
    if (i >= Kpad * 4) return;
    int k = i >> 2, h = i & 3;
    float s = 0.f;
    if (k < Kin)
        for (int c = 0; c < C; ++c) s += W[(size_t)k * (4 * C) + h * C + c] * a[h * C + c];
    w[i] = s;
}

// Bt1 [256, 320]: (block-diag W1 per head | res1)^T
__global__ void build_bt1_kernel(const float* __restrict__ W1, const float* __restrict__ res1,
                                 ushort_t* __restrict__ Bt1) {
    int i = blockIdx.x * blockDim.x + threadIdx.x;
    if (i >= HC1 * K1S) return;
    int c = i / K1S, kk = i - c * K1S;
    float v = 0.f;
    if (kk < 256) {
        int h = kk >> 6, k = kk & 63;
        if (k < F_IN && (c >> 6) == h) v = W1[(size_t)k * HC1 + c];
    } else {
        int k = kk - 256;
        if (k < F_IN) v = res1[(size_t)k * HC1 + c];
    }
    Bt1[i] = f2bf(v);
}

// Bt2 [512, 256]: cols 0..255 = W2, 256..511 = res2, transposed
__global__ void build_bt2_kernel(const float* __restrict__ W2, const float* __restrict__ res2,
                                 ushort_t* __restrict__ Bt2) {
    int i = blockIdx.x * blockDim.x + threadIdx.x;
    if (i >= N2S * HC1) return;
    int c = i / HC1, k = i - c * HC1;
    float v = (c < HC1) ? W2[(size_t)k * HC1 + c] : res2[(size_t)k * HC1 + (c - HC1)];
    Bt2[i] = f2bf(v);
}

__global__ void build_bias2_kernel(const float* __restrict__ b2, float* __restrict__ bias512) {
    int i = blockIdx.x * blockDim.x + threadIdx.x;
    if (i >= N2S) return;
    bias512[i] = (i < HC1) ? 0.f : b2[i - HC1];
}

// Bt3 [121, 1280]: (0.25*W3 per head stacked | res3)^T
__global__ void build_bt3_kernel(const float* __restrict__ W3, const float* __restrict__ res3,
                                 ushort_t* __restrict__ Bt3) {
    int i = blockIdx.x * blockDim.x + threadIdx.x;
    if (i >= NC * K3S) return;
    int c = i / K3S, kk = i - c * K3S;
    float v;
    if (kk < 1024) {
        int h = kk >> 8, k = kk & 255;
        v = 0.25f * W3[(size_t)k * (HEADS * NC) + h * NC + c];
    } else {
        int k = kk - 1024;
        v = res3[(size_t)k * NC + c];
    }
    Bt3[i] = f2bf(v);
}

// ---------------------------------------------------------------- MFMA GEMM (split-A)
// C[M,N] = [A1 | A2][M,K] * Bt[N,K]^T.  k < Ksplit from A1 (lda1), else A2 (lda2).
// K, Ksplit multiples of 64.
#define BM 128
#define BN 128
#define BK 64
#define LDP (BK + 8)

__global__ __launch_bounds__(256)
void gemm_mfma_kernel(const ushort_t* __restrict__ A1, int lda1,
                      const ushort_t* __restrict__ A2, int lda2, int Ksplit,
                      const ushort_t* __restrict__ Bt, const float* __restrict__ bias,
                      float* __restrict__ Cf, ushort_t* __restrict__ Cb,
                      int M, int N, int K, int relu) {
    __shared__ ushort_t As[BM * LDP];
    __shared__ ushort_t Bs[BN * LDP];
    int tid = threadIdx.x;
    int lane = tid & 63;
    int wid = tid >> 6;
    int wm = (wid & 1) * 64, wn = (wid >> 1) * 64;
    int l15 = lane & 15;
    int q8 = (lane >> 4) * 8;
    int m0 = blockIdx.y * BM, n0 = blockIdx.x * BN;

    f32x4 acc[4][4] = {};

    for (int k0 = 0; k0 < K; k0 += BK) {
        #pragma unroll
        for (int it = 0; it < 4; ++it) {
            int c = tid + it * 256;
            int row = c >> 3, c8 = c & 7;
            int k = k0 + c8 * 8;
            ushort8 va = (ushort8)0;
            int gm = m0 + row;
            if (gm < M) {
                if (k < Ksplit) va = *(const ushort8*)&A1[(size_t)gm * lda1 + k];
                else            va = *(const ushort8*)&A2[(size_t)gm * lda2 + (k - Ksplit)];
            }
            *(ushort8*)&As[row * LDP + c8 * 8] = va;
            ushort8 vb = (ushort8)0;
            int gn = n0 + row;
            if (gn < N) vb = *(const ushort8*)&Bt[(size_t)gn * K + k];
            *(ushort8*)&Bs[row * LDP + c8 * 8] = vb;
        }
        __syncthreads();
        #pragma unroll
        for (int kk = 0; kk < BK; kk += 32) {
            bf16x8 af[4], bfr[4];
            #pragma unroll
            for (int mi = 0; mi < 4; ++mi)
                af[mi] = *(const bf16x8*)&As[(wm + mi * 16 + l15) * LDP + kk + q8];
            #pragma unroll
            for (int ni = 0; ni < 4; ++ni)
                bfr[ni] = *(const bf16x8*)&Bs[(wn + ni * 16 + l15) * LDP + kk + q8];
            #pragma unroll
            for (int mi = 0; mi < 4; ++mi)
                #pragma unroll
                for (int ni = 0; ni < 4; ++ni)
                    acc[mi][ni] = __builtin_amdgcn_mfma_f32_16x16x32_bf16(
                        af[mi], bfr[ni], acc[mi][ni], 0, 0, 0);
        }
        __syncthreads();
    }

    #pragma unroll
    for (int mi = 0; mi < 4; ++mi) {
        int mbase = m0 + wm + mi * 16 + (lane >> 4) * 4;
        #pragma unroll
        for (int ni = 0; ni < 4; ++ni) {
            int ncol = n0 + wn + ni * 16 + l15;
            if (ncol >= N) continue;
            float bv = bias ? bias[ncol] : 0.f;
            #pragma unroll
            for (int r = 0; r < 4; ++r) {
                int m = mbase + r;
                if (m >= M) continue;
                float v = acc[mi][ni][r] + bv;
                if (relu) v = fmaxf(v, 0.f);
                if (Cf) Cf[(size_t)m * N + ncol] = v;
                else    Cb[(size_t)m * N + ncol] = f2bf(v);
            }
        }
    }
}

// ---------------------------------------------------------------- logits GEMV
__global__ __launch_bounds__(64)
void logits_gemv_kernel(const ushort_t* __restrict__ X, int K,
                        const float* __restrict__ w_as, const float* __restrict__ w_ad,
                        float* __restrict__ als, float* __restrict__ ald) {
    int n = blockIdx.x, lane = threadIdx.x;
    float ps[HEADS] = {}, pd[HEADS] = {};
    for (int k0 = lane * 4; k0 < K; k0 += 256) {
        ushort4_t xv = *(const ushort4_t*)&X[(size_t)n * K + k0];
        float x[4] = {bf2f(xv.x), bf2f(xv.y), bf2f(xv.z), bf2f(xv.w)};
        #pragma unroll
        for (int j = 0; j < 4; ++j) {
            #pragma unroll
            for (int h = 0; h < HEADS; ++h) {
                ps[h] += x[j] * w_as[(k0 + j) * 4 + h];
                pd[h] += x[j] * w_ad[(k0 + j) * 4 + h];
            }
        }
    }
    #pragma unroll
    for (int off = 32; off; off >>= 1)
        #pragma unroll
        for (int h = 0; h < HEADS; ++h) {
            ps[h] += __shfl_xor(ps[h], off);
            pd[h] += __shfl_xor(pd[h], off);
        }
    if (lane == 0)
        #pragma unroll
        for (int h = 0; h < HEADS; ++h) {
            als[n * HEADS + h] = ps[h];
            ald[n * HEADS + h] = pd[h];
        }
}

// ---------------------------------------------------------------- fused softmax helpers (per-dst block, 1 wave)
// Computes mx/rd (per head) for node d, lane-strided over its edges.
#define SOFTMAX_PREP(als_, ald_)                                              \
    int beg = row_ptr[d], end = row_ptr[d + 1];                               \
    f32x4 aldd = *(const f32x4*)&(ald_)[d * 4];                               \
    float mx[HEADS] = {-1e30f, -1e30f, -1e30f, -1e30f};                       \
    for (int i = beg + lane; i < end; i += 64) {                              \
        f32x4 av = *(const f32x4*)&(als_)[csr_src[i] * 4];                    \
        _Pragma("unroll")                                                     \
        for (int h = 0; h < HEADS; ++h)                                       \
            mx[h] = fmaxf(mx[h], lrelu(av[h] + aldd[h]));                     \
    }                                                                         \
    _Pragma("unroll")                                                         \
    for (int off = 32; off; off >>= 1)                                        \
        _Pragma("unroll")                                                     \
        for (int h = 0; h < HEADS; ++h)                                       \
            mx[h] = fmaxf(mx[h], __shfl_xor(mx[h], off));                     \
    float den[HEADS] = {};                                                    \
    for (int i = beg + lane; i < end; i += 64) {                              \
        f32x4 av = *(const f32x4*)&(als_)[csr_src[i] * 4];                    \
        _Pragma("unroll")                                                     \
        for (int h = 0; h < HEADS; ++h)                                       \
            den[h] += __expf(lrelu(av[h] + aldd[h]) - mx[h]);                 \
    }                                                                         \
    _Pragma("unroll")                                                         \
    for (int off = 32; off; off >>= 1)                                        \
        _Pragma("unroll")                                                     \
        for (int h = 0; h < HEADS; ++h)                                       \
            den[h] += __shfl_xor(den[h], off);                                \
    float rd[HEADS];                                                          \
    _Pragma("unroll")                                                         \
    for (int h = 0; h < HEADS; ++h) rd[h] = 1.f / den[h];

// Per 64-edge chunk: lane-parallel alpha into LDS.
#define ALPHA_CHUNK(als_)                                                     \
    int i = base + lane;                                                      \
    int nvalid = end - base; if (nvalid > 64) nvalid = 64;                    \
    if (i < end) {                                                            \
        int s = csr_src[i];                                                   \
        ssrc[lane] = s;                                                       \
        f32x4 av = *(const f32x4*)&(als_)[s * 4];                             \
        f32x4 a;                                                              \
        _Pragma("unroll")                                                     \
        for (int h = 0; h < HEADS; ++h)                                       \
            a[h] = __expf(lrelu(av[h] + aldd[h]) - mx[h]) * rd[h];            \
        *(f32x4*)&sal[lane * 4] = a;                                          \
    }                                                                         \
    __syncthreads();

// ---------------------------------------------------------------- agg layer 1 (fused alpha; gather x0b 64 cols -> aggx1[N,256])
__global__ __launch_bounds__(64)
void agg1_kernel(const ushort_t* __restrict__ x0b,
                 const float* __restrict__ als, const float* __restrict__ ald,
                 const int* __restrict__ row_ptr, const int* __restrict__ csr_src,
                 ushort_t* __restrict__ aggx) {
    __shared__ int   ssrc[64];
    __shared__ float sal[64 * 4];
    int d = blockIdx.x, lane = threadIdx.x;
    SOFTMAX_PREP(als, ald)
    float acc[HEADS] = {};
    for (int base = beg; base < end; base += 64) {
        ALPHA_CHUNK(als)
        for (int j = 0; j < nvalid; ++j) {
            int s = ssrc[j];
            f32x4 a = *(const f32x4*)&sal[j * 4];
            float xv = bf2f(x0b[(size_t)s * KPAD1 + lane]);
            #pragma unroll
            for (int h = 0; h < HEADS; ++h) acc[h] += a[h] * xv;
        }
        __syncthreads();
    }
    #pragma unroll
    for (int h = 0; h < HEADS; ++h)
        aggx[(size_t)d * HC1 + h * 64 + lane] = f2bf(acc[h]);
}

// ---------------------------------------------------------------- agg layer 2 (fused alpha; gather h2; resid+ReLU; fused layer-3 logits)
__global__ __launch_bounds__(64)
void agg2_kernel(const ushort_t* __restrict__ comb,
                 const float* __restrict__ als, const float* __restrict__ ald,
                 const int* __restrict__ row_ptr, const int* __restrict__ csr_src,
                 const float* __restrict__ w_as3, const float* __restrict__ w_ad3,
                 ushort_t* __restrict__ xnext,
                 float* __restrict__ als3, float* __restrict__ ald3) {
    __shared__ int   ssrc[64];
    __shared__ float sal[64 * 4];
    int d = blockIdx.x, lane = threadIdx.x;
    int hh = lane >> 4;                       // head of cols [lane*4, lane*4+4)
    SOFTMAX_PREP(als, ald)
    float a0 = 0, a1 = 0, a2 = 0, a3 = 0;
    for (int base = beg; base < end; base += 64) {
        ALPHA_CHUNK(als)
        for (int j = 0; j < nvalid; ++j) {
            int s = ssrc[j];
            float al = sal[j * 4 + hh];
            ushort4_t xv = *(const ushort4_t*)&comb[(size_t)s * N2S + lane * 4];
            a0 += al * bf2f(xv.x); a1 += al * bf2f(xv.y);
            a2 += al * bf2f(xv.z); a3 += al * bf2f(xv.w);
        }
        __syncthreads();
    }
    ushort4_t rv = *(const ushort4_t*)&comb[(size_t)d * N2S + 256 + lane * 4];
    float v0 = fmaxf(a0 + bf2f(rv.x), 0.f);
    float v1 = fmaxf(a1 + bf2f(rv.y), 0.f);
    float v2 = fmaxf(a2 + bf2f(rv.z), 0.f);
    float v3 = fmaxf(a3 + bf2f(rv.w), 0.f);
    ushort4_t o;
    o.x = f2bf(v0); o.y = f2bf(v1); o.z = f2bf(v2); o.w = f2bf(v3);
    *(ushort4_t*)&xnext[(size_t)d * HC1 + lane * 4] = o;
    // fused layer-3 logits: als3[d,h] = x2[d,:]·w_as3[:,h]
    f32x4 ps = (f32x4)0.f, pd = (f32x4)0.f;
    float v[4] = {v0, v1, v2, v3};
    #pragma unroll
    for (int j = 0; j < 4; ++j) {
        f32x4 wsj = *(const f32x4*)&w_as3[(lane * 4 + j) * 4];
        f32x4 wdj = *(const f32x4*)&w_ad3[(lane * 4 + j) * 4];
        ps += v[j] * wsj;
        pd += v[j] * wdj;
    }
    #pragma unroll
    for (int off = 32; off; off >>= 1) {
        #pragma unroll
        for (int h = 0; h < HEADS; ++h) {
            ps[h] += __shfl_xor(ps[h], off);
            pd[h] += __shfl_xor(pd[h], off);
        }
    }
    if (lane == 0) {
        *(f32x4*)&als3[d * 4] = ps;
        *(f32x4*)&ald3[d * 4] = pd;
    }
}

// ---------------------------------------------------------------- agg layer 3 (fused alpha; gather x2 256 cols -> aggx3[N,1024])
__global__ __launch_bounds__(64)
void agg3_kernel(const ushort_t* __restrict__ x2b,
                 const float* __restrict__ als, const float* __restrict__ ald,
                 const int* __restrict__ row_ptr, const int* __restrict__ csr_src,
                 ushort_t* __restrict__ aggx) {
    __shared__ int   ssrc[64];
    __shared__ float sal[64 * 4];
    int d = blockIdx.x, lane = threadIdx.x;
    SOFTMAX_PREP(als, ald)
    float acc[HEADS][4] = {};
    for (int base = beg; base < end; base += 64) {
        ALPHA_CHUNK(als)
        for (int j = 0; j < nvalid; ++j) {
            int s = ssrc[j];
            f32x4 a = *(const f32x4*)&sal[j * 4];
            ushort4_t xv = *(const ushort4_t*)&x2b[(size_t)s * HC1 + lane * 4];
            float x0 = bf2f(xv.x), x1 = bf2f(xv.y), x2 = bf2f(xv.z), x3 = bf2f(xv.w);
            #pragma unroll
            for (int h = 0; h < HEADS; ++h) {
                acc[h][0] += a[h] * x0; acc[h][1] += a[h] * x1;
                acc[h][2] += a[h] * x2; acc[h][3] += a[h] * x3;
            }
        }
        __syncthreads();
    }
    #pragma unroll
    for (int h = 0; h < HEADS; ++h) {
        ushort4_t o;
        o.x = f2bf(acc[h][0]); o.y = f2bf(acc[h][1]);
        o.z = f2bf(acc[h][2]); o.w = f2bf(acc[h][3]);
        *(ushort4_t*)&aggx[(size_t)d * 1024 + h * HC1 + lane * 4] = o;
    }
}

// ---------------------------------------------------------------- launch
extern "C" void kernel_launch(void* const* d_in, const int* in_sizes, int n_in,
                              void* d_out, int out_size, void* d_ws, size_t ws_size,
                              hipStream_t stream) {
    const float* x0   = (const float*)d_in[0];
    const int*   ei   = (const int*)d_in[1];
    const float* W1   = (const float*)d_in[2];
    const float* as1  = (const float*)d_in[3];
    const float* ad1  = (const float*)d_in[4];
    const float* res1 = (const float*)d_in[5];
    const float* b1   = (const float*)d_in[6];
    const float* W2   = (const float*)d_in[7];
    const float* as2  = (const float*)d_in[8];
    const float* ad2  = (const float*)d_in[9];
    const float* res2 = (const float*)d_in[10];
    const float* b2   = (const float*)d_in[11];
    const float* W3   = (const float*)d_in[12];
    const float* as3  = (const float*)d_in[13];
    const float* ad3  = (const float*)d_in[14];
    const float* res3 = (const float*)d_in[15];
    const float* b3   = (const float*)d_in[16];

    char* p = (char*)d_ws;
    auto alloc = [&](size_t bytes) -> void* {
        void* r = (void*)p;
        p += (bytes + 255) & ~(size_t)255;
        return r;
    };
    int*      cnt     = (int*)alloc((size_t)NNODES * 4);
    int*      incl    = (int*)alloc((size_t)NNODES * 4);
    int*      bsums   = (int*)alloc((size_t)SCB * 4);
    int*      row_ptr = (int*)alloc((size_t)(NNODES + 1) * 4);
    int*      cursor  = (int*)alloc((size_t)NNODES * 4);
    int*      csr_src = (int*)alloc((size_t)NTOT * 4);
    float*    als     = (float*)alloc((size_t)NNODES * HEADS * 4);
    float*    ald     = (float*)alloc((size_t)NNODES * HEADS * 4);
    float*    als3    = (float*)alloc((size_t)NNODES * HEADS * 4);
    float*    ald3    = (float*)alloc((size_t)NNODES * HEADS * 4);
    ushort_t* x0b     = (ushort_t*)alloc((size_t)NNODES * KPAD1 * 2);
    ushort_t* x2      = (ushort_t*)alloc((size_t)NNODES * HC1 * 2);
    ushort_t* Bt1     = (ushort_t*)alloc((size_t)HC1 * K1S * 2);
    ushort_t* Bt2     = (ushort_t*)alloc((size_t)N2S * HC1 * 2);
    float*    bias512 = (float*)alloc((size_t)N2S * 4);
    ushort_t* Bt3     = (ushort_t*)alloc((size_t)NC * K3S * 2);
    float*    w_as1   = (float*)alloc((size_t)KPAD1 * 4 * 4);
    float*    w_ad1   = (float*)alloc((size_t)KPAD1 * 4 * 4);
    float*    w_as2   = (float*)alloc((size_t)HC1 * 4 * 4);
    float*    w_ad2   = (float*)alloc((size_t)HC1 * 4 * 4);
    float*    w_as3   = (float*)alloc((size_t)HC1 * 4 * 4);
    float*    w_ad3   = (float*)alloc((size_t)HC1 * 4 * 4);
    // aliased region: layer-1/2 temporaries, reused as aggx3 [N,1024] bf16 (102.4 MB)
    char*     big     = (char*)alloc((size_t)NNODES * 1024 * 2);
    ushort_t* aggx1   = (ushort_t*)big;                                  // [N,256]
    ushort_t* x1      = (ushort_t*)(big + (size_t)NNODES * HC1 * 2);     // [N,256]
    ushort_t* comb    = (ushort_t*)(big + (size_t)NNODES * HC1 * 4);     // [N,512]
    ushort_t* aggx3   = (ushort_t*)big;                                  // [N,1024] (layer 3)

    hipMemsetAsync(cnt, 0, (size_t)NNODES * 4, stream);

    int tb = 256;
    int nscan = (NNODES + SCB - 1) / SCB;
    count_kernel<<<(NTOT + tb - 1) / tb, tb, 0, stream>>>(ei, cnt);
    scan1_kernel<<<nscan, SCB, 0, stream>>>(cnt, incl, bsums, NNODES);
    scan2_kernel<<<1, SCB, 0, stream>>>(bsums, nscan);
    scan3_kernel<<<nscan, SCB, 0, stream>>>(cnt, incl, bsums, row_ptr, cursor, NNODES);
    scatter_kernel<<<(NTOT + tb - 1) / tb, tb, 0, stream>>>(ei, cursor, csr_src);

    // weight prep
    conv_pad_kernel<<<(NNODES * KPAD1 + tb - 1) / tb, tb, 0, stream>>>(x0, x0b, NNODES, F_IN, KPAD1);
    build_bt1_kernel<<<(HC1 * K1S + tb - 1) / tb, tb, 0, stream>>>(W1, res1, Bt1);
    build_bt2_kernel<<<(N2S * HC1 + tb - 1) / tb, tb, 0, stream>>>(W2, res2, Bt2);
    build_bias2_kernel<<<(N2S + tb - 1) / tb, tb, 0, stream>>>(b2, bias512);
    build_bt3_kernel<<<(NC * K3S + tb - 1) / tb, tb, 0, stream>>>(W3, res3, Bt3);
    build_w_kernel<<<(KPAD1 * 4 + tb - 1) / tb, tb, 0, stream>>>(W1, as1, w_as1, F_IN, KPAD1, C1);
    build_w_kernel<<<(KPAD1 * 4 + tb - 1) / tb, tb, 0, stream>>>(W1, ad1, w_ad1, F_IN, KPAD1, C1);
    build_w_kernel<<<(HC1 * 4 + tb - 1) / tb, tb, 0, stream>>>(W2, as2, w_as2, HC1, HC1, C1);
    build_w_kernel<<<(HC1 * 4 + tb - 1) / tb, tb, 0, stream>>>(W2, ad2, w_ad2, HC1, HC1, C1);
    build_w_kernel<<<(HC1 * 4 + tb - 1) / tb, tb, 0, stream>>>(W3, as3, w_as3, HC1, HC1, NC);
    build_w_kernel<<<(HC1 * 4 + tb - 1) / tb, tb, 0, stream>>>(W3, ad3, w_ad3, HC1, HC1, NC);

    auto gemm = [&](const ushort_t* A1, int lda1, const ushort_t* A2, int lda2, int Ksplit,
                    const ushort_t* Bt, const float* bias,
                    float* Cf, ushort_t* Cb, int M, int Nn, int K, int relu) {
        dim3 g((Nn + BN - 1) / BN, (M + BM - 1) / BM);
        gemm_mfma_kernel<<<g, 256, 0, stream>>>(A1, lda1, A2, lda2, Ksplit, Bt, bias,
                                                Cf, Cb, M, Nn, K, relu);
    };

    // ---- layer 1 (aggregate-then-transform; GEMM reads [aggx1 | x0b])
    logits_gemv_kernel<<<NNODES, 64, 0, stream>>>(x0b, KPAD1, w_as1, w_ad1, als, ald);
    agg1_kernel<<<NNODES, 64, 0, stream>>>(x0b, als, ald, row_ptr, csr_src, aggx1);
    gemm(aggx1, HC1, x0b, KPAD1, HC1, Bt1, b1, nullptr, x1, NNODES, HC1, K1S, 1);

    // ---- layer 2 (stacked GEMM [h2|resid]; agg2 also emits layer-3 logits)
    gemm(x1, HC1, x1, HC1, HC1, Bt2, bias512, nullptr, comb, NNODES, N2S, HC1, 0);
    logits_gemv_kernel<<<NNODES, 64, 0, stream>>>(x1, HC1, w_as2, w_ad2, als, ald);
    agg2_kernel<<<NNODES, 64, 0, stream>>>(comb, als, ald, row_ptr, csr_src,
                                           w_as3, w_ad3, x2, als3, ald3);

    // ---- layer 3 (aggregate-then-transform; GEMM reads [aggx3 | x2])
    agg3_kernel<<<NNODES, 64, 0, stream>>>(x2, als3, ald3, row_ptr, csr_src, aggx3);
    gemm(aggx3, 1024, x2, HC1, 1024, Bt3, b3, (float*)d_out, nullptr, NNODES, NC, K3S, 0);
}

// Round 8
// 654.687 us; speedup vs baseline: 2.6665x; 1.1347x over previous
//
#include <hip/hip_runtime.h>

#define NNODES 50000
#define NEDGES 800000
#define NTOT   (NEDGES + NNODES)   // edges + self loops
#define F_IN   50
#define KPAD1  64                  // F_IN padded to 64
#define HEADS  4
#define C1     64
#define HC1    256                 // HEADS*C1
#define NC     121
#define K1S    320                 // layer1 GEMM K: 256 (agg) + 64 (x0)
#define K3S    1280                // layer3 GEMM K: 1024 (agg) + 256 (x2)
#define N2S    512                 // layer2 GEMM N: 256 (W2) + 256 (res2)

typedef unsigned short ushort_t;
typedef __attribute__((ext_vector_type(4))) unsigned short ushort4_t;
typedef __attribute__((ext_vector_type(8))) unsigned short ushort8;
typedef __attribute__((ext_vector_type(8))) __bf16 bf16x8;
typedef __attribute__((ext_vector_type(4))) float f32x4;

__device__ __forceinline__ ushort_t f2bf(float f) {
    union { float f; unsigned int u; } v; v.f = f;
    unsigned int u = v.u;
    return (ushort_t)((u + 0x7fffu + ((u >> 16) & 1u)) >> 16);   // RNE
}
__device__ __forceinline__ float bf2f(ushort_t s) {
    union { unsigned int u; float f; } v; v.u = ((unsigned int)s) << 16;
    return v.f;
}
__device__ __forceinline__ float lrelu(float x) { return x > 0.f ? x : 0.2f * x; }

// ---------------------------------------------------------------- CSR build
__global__ void count_kernel(const int* __restrict__ ei, int* __restrict__ cnt) {
    int i = blockIdx.x * blockDim.x + threadIdx.x;
    if (i >= NTOT) return;
    int d = (i < NEDGES) ? ei[NEDGES + i] : (i - NEDGES);
    if ((unsigned)d >= NNODES) d = 0;
    atomicAdd(&cnt[d], 1);
}

#define SCB 256
__global__ __launch_bounds__(SCB)
void scan1_kernel(const int* __restrict__ cnt, int* __restrict__ incl,
                  int* __restrict__ bsums, int n) {
    __shared__ int buf[SCB];
    int b = blockIdx.x, tid = threadIdx.x;
    int i = b * SCB + tid;
    int v = (i < n) ? cnt[i] : 0;
    buf[tid] = v;
    __syncthreads();
    for (int off = 1; off < SCB; off <<= 1) {
        int t = (tid >= off) ? buf[tid - off] : 0;
        __syncthreads();
        buf[tid] += t;
        __syncthreads();
    }
    if (i < n) incl[i] = buf[tid];
    if (tid == SCB - 1) bsums[b] = buf[tid];
}

__global__ __launch_bounds__(SCB)
void scan2_kernel(int* __restrict__ bsums, int nb) {
    __shared__ int buf[SCB];
    int tid = threadIdx.x;
    int v = (tid < nb) ? bsums[tid] : 0;
    buf[tid] = v;
    __syncthreads();
    for (int off = 1; off < SCB; off <<= 1) {
        int t = (tid >= off) ? buf[tid - off] : 0;
        __syncthreads();
        buf[tid] += t;
        __syncthreads();
    }
    if (tid < nb) bsums[tid] = buf[tid] - v;   // exclusive
}

__global__ __launch_bounds__(SCB)
void scan3_kernel(const int* __restrict__ cnt, const int* __restrict__ incl,
                  const int* __restrict__ bsums, int* __restrict__ row_ptr,
                  int* __restrict__ cursor, int n) {
    int b = blockIdx.x, tid = threadIdx.x;
    int i = b * SCB + tid;
    if (i >= n) return;
    int e = bsums[b] + incl[i] - cnt[i];
    row_ptr[i] = e; cursor[i] = e;
    if (i == n - 1) row_ptr[n] = NTOT;
}

__global__ void scatter_kernel(const int* __restrict__ ei, int* __restrict__ cursor,
                               int* __restrict__ csr_src) {
    int i = blockIdx.x * blockDim.x + threadIdx.x;
    if (i >= NTOT) return;
    int s, d;
    if (i < NEDGES) { s = ei[i]; d = ei[NEDGES + i]; }
    else            { s = d = i - NEDGES; }
    if ((unsigned)d >= NNODES) d = 0;
    if ((unsigned)s >= NNODES) s = 0;
    int pos = atomicAdd(&cursor[d], 1);
    csr_src[pos] = s;
}

// ---------------------------------------------------------------- merged prep kernel
// flat-index ladder over all weight converts/builders
#define SZ_A (NNODES * KPAD1)     // x0b
#define SZ_B (HC1 * K1S)          // Bt1
#define SZ_C (N2S * HC1)          // Bt2
#define SZ_D (N2S)                // bias512
#define SZ_E (NC * K3S)           // Bt3
#define SZ_F (KPAD1 * 4)          // w_as1 / w_ad1
#define SZ_G (HC1 * 4)            // w_as2 / w_ad2 / w_as3 / w_ad3
#define PREP_TOTAL (SZ_A + SZ_B + SZ_C + SZ_D + SZ_E + 2 * SZ_F + 4 * SZ_G)

__global__ __launch_bounds__(256)
void prep_kernel(const float* __restrict__ x0,
                 const float* __restrict__ W1, const float* __restrict__ res1,
                 const float* __restrict__ W2, const float* __restrict__ res2,
                 const float* __restrict__ W3, const float* __restrict__ res3,
                 const float* __restrict__ as1, const float* __restrict__ ad1,
                 const float* __restrict__ as2, const float* __restrict__ ad2,
                 const float* __restrict__ as3, const float* __restrict__ ad3,
                 const float* __restrict__ b2,
                 ushort_t* __restrict__ x0b, ushort_t* __restrict__ Bt1,
                 ushort_t* __restrict__ Bt2, ushort_t* __restrict__ Bt3,
                 float* __restrict__ bias512,
                 float* __restrict__ w_as1, float* __restrict__ w_ad1,
                 float* __restrict__ w_as2, float* __restrict__ w_ad2,
                 float* __restrict__ w_as3, float* __restrict__ w_ad3) {
    int i = blockIdx.x * 256 + threadIdx.x;
    if (i < SZ_A) {                                  // x0 -> bf16 padded
        int m = i >> 6, k = i & 63;
        x0b[i] = (k < F_IN) ? f2bf(x0[(size_t)m * F_IN + k]) : (ushort_t)0;
        return;
    }
    i -= SZ_A;
    if (i < SZ_B) {                                  // Bt1 [256,320]
        int c = i / K1S, kk = i - c * K1S;
        float v = 0.f;
        if (kk < 256) {
            int h = kk >> 6, k = kk & 63;
            if (k < F_IN && (c >> 6) == h) v = W1[(size_t)k * HC1 + c];
        } else {
            int k = kk - 256;
            if (k < F_IN) v = res1[(size_t)k * HC1 + c];
        }
        Bt1[i] = f2bf(v);
        return;
    }
    i -= SZ_B;
    if (i < SZ_C) {                                  // Bt2 [512,256]
        int c = i / HC1, k = i - c * HC1;
        float v = (c < HC1) ? W2[(size_t)k * HC1 + c] : res2[(size_t)k * HC1 + (c - HC1)];
        Bt2[i] = f2bf(v);
        return;
    }
    i -= SZ_C;
    if (i < SZ_D) {                                  // bias512
        bias512[i] = (i < HC1) ? 0.f : b2[i - HC1];
        return;
    }
    i -= SZ_D;
    if (i < SZ_E) {                                  // Bt3 [121,1280]
        int c = i / K3S, kk = i - c * K3S;
        float v;
        if (kk < 1024) {
            int h = kk >> 8, k = kk & 255;
            v = 0.25f * W3[(size_t)k * (HEADS * NC) + h * NC + c];
        } else {
            int k = kk - 1024;
            v = res3[(size_t)k * NC + c];
        }
        Bt3[i] = f2bf(v);
        return;
    }
    i -= SZ_E;
    if (i < 2 * SZ_F) {                              // w_as1 / w_ad1 (Kin=50, C=64)
        const float* a = (i < SZ_F) ? as1 : ad1;
        float* w = (i < SZ_F) ? w_as1 : w_ad1;
        int ii = (i < SZ_F) ? i : i - SZ_F;
        int k = ii >> 2, h = ii & 3;
        float s = 0.f;
        if (k < F_IN)
            for (int c = 0; c < C1; ++c) s += W1[(size_t)k * HC1 + h * C1 + c] * a[h * C1 + c];
        w[ii] = s;
        return;
    }
    i -= 2 * SZ_F;
    {                                                // w_as2/w_ad2 (C=64), w_as3/w_ad3 (C=121)
        int grp = i / SZ_G, ii = i - grp * SZ_G;
        int k = ii >> 2, h = ii & 3;
        float s = 0.f;
        if (grp < 2) {
            const float* a = grp ? ad2 : as2;
            for (int c = 0; c < C1; ++c) s += W2[(size_t)k * HC1 + h * C1 + c] * a[h * C1 + c];
            (grp ? w_ad2 : w_as2)[ii] = s;
        } else {
            const float* a = (grp == 3) ? ad3 : as3;
            for (int c = 0; c < NC; ++c) s += W3[(size_t)k * (HEADS * NC) + h * NC + c] * a[h * NC + c];
            ((grp == 3) ? w_ad3 : w_as3)[ii] = s;
        }
    }
}

// ---------------------------------------------------------------- MFMA GEMM (split-A)
#define BM 128
#define BN 128
#define BK 64
#define LDP (BK + 8)

__global__ __launch_bounds__(256)
void gemm_mfma_kernel(const ushort_t* __restrict__ A1, int lda1,
                      const ushort_t* __restrict__ A2, int lda2, int Ksplit,
                      const ushort_t* __restrict__ Bt, const float* __restrict__ bias,
                      float* __restrict__ Cf, ushort_t* __restrict__ Cb,
                      int M, int N, int K, int relu) {
    __shared__ ushort_t As[BM * LDP];
    __shared__ ushort_t Bs[BN * LDP];
    int tid = threadIdx.x;
    int lane = tid & 63;
    int wid = tid >> 6;
    int wm = (wid & 1) * 64, wn = (wid >> 1) * 64;
    int l15 = lane & 15;
    int q8 = (lane >> 4) * 8;
    int m0 = blockIdx.y * BM, n0 = blockIdx.x * BN;

    f32x4 acc[4][4] = {};

    for (int k0 = 0; k0 < K; k0 += BK) {
        #pragma unroll
        for (int it = 0; it < 4; ++it) {
            int c = tid + it * 256;
            int row = c >> 3, c8 = c & 7;
            int k = k0 + c8 * 8;
            ushort8 va = (ushort8)0;
            int gm = m0 + row;
            if (gm < M) {
                if (k < Ksplit) va = *(const ushort8*)&A1[(size_t)gm * lda1 + k];
                else            va = *(const ushort8*)&A2[(size_t)gm * lda2 + (k - Ksplit)];
            }
            *(ushort8*)&As[row * LDP + c8 * 8] = va;
            ushort8 vb = (ushort8)0;
            int gn = n0 + row;
            if (gn < N) vb = *(const ushort8*)&Bt[(size_t)gn * K + k];
            *(ushort8*)&Bs[row * LDP + c8 * 8] = vb;
        }
        __syncthreads();
        #pragma unroll
        for (int kk = 0; kk < BK; kk += 32) {
            bf16x8 af[4], bfr[4];
            #pragma unroll
            for (int mi = 0; mi < 4; ++mi)
                af[mi] = *(const bf16x8*)&As[(wm + mi * 16 + l15) * LDP + kk + q8];
            #pragma unroll
            for (int ni = 0; ni < 4; ++ni)
                bfr[ni] = *(const bf16x8*)&Bs[(wn + ni * 16 + l15) * LDP + kk + q8];
            #pragma unroll
            for (int mi = 0; mi < 4; ++mi)
                #pragma unroll
                for (int ni = 0; ni < 4; ++ni)
                    acc[mi][ni] = __builtin_amdgcn_mfma_f32_16x16x32_bf16(
                        af[mi], bfr[ni], acc[mi][ni], 0, 0, 0);
        }
        __syncthreads();
    }

    #pragma unroll
    for (int mi = 0; mi < 4; ++mi) {
        int mbase = m0 + wm + mi * 16 + (lane >> 4) * 4;
        #pragma unroll
        for (int ni = 0; ni < 4; ++ni) {
            int ncol = n0 + wn + ni * 16 + l15;
            if (ncol >= N) continue;
            float bv = bias ? bias[ncol] : 0.f;
            #pragma unroll
            for (int r = 0; r < 4; ++r) {
                int m = mbase + r;
                if (m >= M) continue;
                float v = acc[mi][ni][r] + bv;
                if (relu) v = fmaxf(v, 0.f);
                if (Cf) Cf[(size_t)m * N + ncol] = v;
                else    Cb[(size_t)m * N + ncol] = f2bf(v);
            }
        }
    }
}

// ---------------------------------------------------------------- logits GEMV
__global__ __launch_bounds__(64)
void logits_gemv_kernel(const ushort_t* __restrict__ X, int K,
                        const float* __restrict__ w_as, const float* __restrict__ w_ad,
                        float* __restrict__ als, float* __restrict__ ald) {
    int n = blockIdx.x, lane = threadIdx.x;
    float ps[HEADS] = {}, pd[HEADS] = {};
    for (int k0 = lane * 4; k0 < K; k0 += 256) {
        ushort4_t xv = *(const ushort4_t*)&X[(size_t)n * K + k0];
        float x[4] = {bf2f(xv.x), bf2f(xv.y), bf2f(xv.z), bf2f(xv.w)};
        #pragma unroll
        for (int j = 0; j < 4; ++j) {
            #pragma unroll
            for (int h = 0; h < HEADS; ++h) {
                ps[h] += x[j] * w_as[(k0 + j) * 4 + h];
                pd[h] += x[j] * w_ad[(k0 + j) * 4 + h];
            }
        }
    }
    #pragma unroll
    for (int off = 32; off; off >>= 1)
        #pragma unroll
        for (int h = 0; h < HEADS; ++h) {
            ps[h] += __shfl_xor(ps[h], off);
            pd[h] += __shfl_xor(pd[h], off);
        }
    if (lane == 0)
        #pragma unroll
        for (int h = 0; h < HEADS; ++h) {
            als[n * HEADS + h] = ps[h];
            ald[n * HEADS + h] = pd[h];
        }
}

// ---------------------------------------------------------------- softmax max pass (per-dst, 1 wave)
#define MAX_PASS(als_, ald_)                                                  \
    int beg = row_ptr[d], end = row_ptr[d + 1];                               \
    f32x4 aldd = *(const f32x4*)&(ald_)[d * 4];                               \
    float mx[HEADS] = {-1e30f, -1e30f, -1e30f, -1e30f};                       \
    for (int i = beg + lane; i < end; i += 64) {                              \
        f32x4 av = *(const f32x4*)&(als_)[csr_src[i] * 4];                    \
        _Pragma("unroll")                                                     \
        for (int h = 0; h < HEADS; ++h)                                       \
            mx[h] = fmaxf(mx[h], lrelu(av[h] + aldd[h]));                     \
    }                                                                         \
    _Pragma("unroll")                                                         \
    for (int off = 32; off; off >>= 1)                                        \
        _Pragma("unroll")                                                     \
        for (int h = 0; h < HEADS; ++h)                                       \
            mx[h] = fmaxf(mx[h], __shfl_xor(mx[h], off));

// per 64-edge chunk: unnormalized e into LDS, partial den in regs
#define E_CHUNK(als_)                                                         \
    int i = base + lane;                                                      \
    int nv = end - base; if (nv > 64) nv = 64;                                \
    if (i < end) {                                                            \
        int s = csr_src[i];                                                   \
        ssrc[lane] = s;                                                       \
        f32x4 av = *(const f32x4*)&(als_)[s * 4];                             \
        f32x4 e;                                                              \
        _Pragma("unroll")                                                     \
        for (int h = 0; h < HEADS; ++h) {                                     \
            e[h] = __expf(lrelu(av[h] + aldd[h]) - mx[h]);                    \
            den[h] += e[h];                                                   \
        }                                                                     \
        *(f32x4*)&se[lane * 4] = e;                                           \
    }                                                                         \
    __syncthreads();

#define DEN_REDUCE                                                            \
    _Pragma("unroll")                                                         \
    for (int off = 32; off; off >>= 1)                                        \
        _Pragma("unroll")                                                     \
        for (int h = 0; h < HEADS; ++h)                                       \
            den[h] += __shfl_xor(den[h], off);                                \
    float rd[HEADS];                                                          \
    _Pragma("unroll")                                                         \
    for (int h = 0; h < HEADS; ++h) rd[h] = 1.f / den[h];

// ---------------------------------------------------------------- agg layer 1 (gather x0b 64 cols -> aggx1[N,256])
__global__ __launch_bounds__(64)
void agg1_kernel(const ushort_t* __restrict__ x0b,
                 const float* __restrict__ als, const float* __restrict__ ald,
                 const int* __restrict__ row_ptr, const int* __restrict__ csr_src,
                 ushort_t* __restrict__ aggx) {
    __shared__ int   ssrc[64];
    __shared__ float se[64 * 4];
    int d = blockIdx.x, lane = threadIdx.x;
    MAX_PASS(als, ald)
    float den[HEADS] = {};
    float acc[HEADS] = {};
    for (int base = beg; base < end; base += 64) {
        E_CHUNK(als)
        int j = 0;
        for (; j + 4 <= nv; j += 4) {
            int s0 = ssrc[j], s1 = ssrc[j + 1], s2 = ssrc[j + 2], s3 = ssrc[j + 3];
            f32x4 e0 = *(const f32x4*)&se[j * 4];
            f32x4 e1 = *(const f32x4*)&se[(j + 1) * 4];
            f32x4 e2 = *(const f32x4*)&se[(j + 2) * 4];
            f32x4 e3 = *(const f32x4*)&se[(j + 3) * 4];
            float x0v = bf2f(x0b[(size_t)s0 * KPAD1 + lane]);
            float x1v = bf2f(x0b[(size_t)s1 * KPAD1 + lane]);
            float x2v = bf2f(x0b[(size_t)s2 * KPAD1 + lane]);
            float x3v = bf2f(x0b[(size_t)s3 * KPAD1 + lane]);
            #pragma unroll
            for (int h = 0; h < HEADS; ++h)
                acc[h] += e0[h] * x0v + e1[h] * x1v + e2[h] * x2v + e3[h] * x3v;
        }
        for (; j < nv; ++j) {
            int s = ssrc[j];
            f32x4 e = *(const f32x4*)&se[j * 4];
            float xv = bf2f(x0b[(size_t)s * KPAD1 + lane]);
            #pragma unroll
            for (int h = 0; h < HEADS; ++h) acc[h] += e[h] * xv;
        }
        __syncthreads();
    }
    DEN_REDUCE
    #pragma unroll
    for (int h = 0; h < HEADS; ++h)
        aggx[(size_t)d * HC1 + h * 64 + lane] = f2bf(acc[h] * rd[h]);
}

// ---------------------------------------------------------------- agg layer 2 (gather h2; resid+ReLU; fused layer-3 logits)
__global__ __launch_bounds__(64)
void agg2_kernel(const ushort_t* __restrict__ comb,
                 const float* __restrict__ als, const float* __restrict__ ald,
                 const int* __restrict__ row_ptr, const int* __restrict__ csr_src,
                 const float* __restrict__ w_as3, const float* __restrict__ w_ad3,
                 ushort_t* __restrict__ xnext,
                 float* __restrict__ als3, float* __restrict__ ald3) {
    __shared__ int   ssrc[64];
    __shared__ float se[64 * 4];
    int d = blockIdx.x, lane = threadIdx.x;
    int hh = lane >> 4;                       // head of cols [lane*4, lane*4+4)
    MAX_PASS(als, ald)
    float den[HEADS] = {};
    float a0 = 0, a1 = 0, a2 = 0, a3 = 0;
    for (int base = beg; base < end; base += 64) {
        E_CHUNK(als)
        int j = 0;
        for (; j + 4 <= nv; j += 4) {
            int s0 = ssrc[j], s1 = ssrc[j + 1], s2 = ssrc[j + 2], s3 = ssrc[j + 3];
            float e0 = se[j * 4 + hh], e1 = se[(j + 1) * 4 + hh];
            float e2 = se[(j + 2) * 4 + hh], e3 = se[(j + 3) * 4 + hh];
            ushort4_t v0 = *(const ushort4_t*)&comb[(size_t)s0 * N2S + lane * 4];
            ushort4_t v1 = *(const ushort4_t*)&comb[(size_t)s1 * N2S + lane * 4];
            ushort4_t v2 = *(const ushort4_t*)&comb[(size_t)s2 * N2S + lane * 4];
            ushort4_t v3 = *(const ushort4_t*)&comb[(size_t)s3 * N2S + lane * 4];
            a0 += e0 * bf2f(v0.x) + e1 * bf2f(v1.x) + e2 * bf2f(v2.x) + e3 * bf2f(v3.x);
            a1 += e0 * bf2f(v0.y) + e1 * bf2f(v1.y) + e2 * bf2f(v2.y) + e3 * bf2f(v3.y);
            a2 += e0 * bf2f(v0.z) + e1 * bf2f(v1.z) + e2 * bf2f(v2.z) + e3 * bf2f(v3.z);
            a3 += e0 * bf2f(v0.w) + e1 * bf2f(v1.w) + e2 * bf2f(v2.w) + e3 * bf2f(v3.w);
        }
        for (; j < nv; ++j) {
            int s = ssrc[j];
            float e = se[j * 4 + hh];
            ushort4_t xv = *(const ushort4_t*)&comb[(size_t)s * N2S + lane * 4];
            a0 += e * bf2f(xv.x); a1 += e * bf2f(xv.y);
            a2 += e * bf2f(xv.z); a3 += e * bf2f(xv.w);
        }
        __syncthreads();
    }
    DEN_REDUCE
    float r = rd[hh];
    ushort4_t rv = *(const ushort4_t*)&comb[(size_t)d * N2S + 256 + lane * 4];
    float v0 = fmaxf(a0 * r + bf2f(rv.x), 0.f);
    float v1 = fmaxf(a1 * r + bf2f(rv.y), 0.f);
    float v2 = fmaxf(a2 * r + bf2f(rv.z), 0.f);
    float v3 = fmaxf(a3 * r + bf2f(rv.w), 0.f);
    ushort4_t o;
    o.x = f2bf(v0); o.y = f2bf(v1); o.z = f2bf(v2); o.w = f2bf(v3);
    *(ushort4_t*)&xnext[(size_t)d * HC1 + lane * 4] = o;
    // fused layer-3 logits: als3[d,h] = x2[d,:]·w_as3[:,h]
    f32x4 ps = (f32x4)0.f, pd = (f32x4)0.f;
    float v[4] = {v0, v1, v2, v3};
    #pragma unroll
    for (int j = 0; j < 4; ++j) {
        f32x4 wsj = *(const f32x4*)&w_as3[(lane * 4 + j) * 4];
        f32x4 wdj = *(const f32x4*)&w_ad3[(lane * 4 + j) * 4];
        ps += v[j] * wsj;
        pd += v[j] * wdj;
    }
    #pragma unroll
    for (int off = 32; off; off >>= 1) {
        #pragma unroll
        for (int h = 0; h < HEADS; ++h) {
            ps[h] += __shfl_xor(ps[h], off);
            pd[h] += __shfl_xor(pd[h], off);
        }
    }
    if (lane == 0) {
        *(f32x4*)&als3[d * 4] = ps;
        *(f32x4*)&ald3[d * 4] = pd;
    }
}

// ---------------------------------------------------------------- agg layer 3 (gather x2 256 cols -> aggx3[N,1024])
__global__ __launch_bounds__(64)
void agg3_kernel(const ushort_t* __restrict__ x2b,
                 const float* __restrict__ als, const float* __restrict__ ald,
                 const int* __restrict__ row_ptr, const int* __restrict__ csr_src,
                 ushort_t* __restrict__ aggx) {
    __shared__ int   ssrc[64];
    __shared__ float se[64 * 4];
    int d = blockIdx.x, lane = threadIdx.x;
    MAX_PASS(als, ald)
    float den[HEADS] = {};
    float acc[HEADS][4] = {};
    for (int base = beg; base < end; base += 64) {
        E_CHUNK(als)
        int j = 0;
        for (; j + 4 <= nv; j += 4) {
            int s0 = ssrc[j], s1 = ssrc[j + 1], s2 = ssrc[j + 2], s3 = ssrc[j + 3];
            f32x4 e0 = *(const f32x4*)&se[j * 4];
            f32x4 e1 = *(const f32x4*)&se[(j + 1) * 4];
            f32x4 e2 = *(const f32x4*)&se[(j + 2) * 4];
            f32x4 e3 = *(const f32x4*)&se[(j + 3) * 4];
            ushort4_t v0 = *(const ushort4_t*)&x2b[(size_t)s0 * HC1 + lane * 4];
            ushort4_t v1 = *(const ushort4_t*)&x2b[(size_t)s1 * HC1 + lane * 4];
            ushort4_t v2 = *(const ushort4_t*)&x2b[(size_t)s2 * HC1 + lane * 4];
            ushort4_t v3 = *(const ushort4_t*)&x2b[(size_t)s3 * HC1 + lane * 4];
            float x00 = bf2f(v0.x), x01 = bf2f(v0.y), x02 = bf2f(v0.z), x03 = bf2f(v0.w);
            float x10 = bf2f(v1.x), x11 = bf2f(v1.y), x12 = bf2f(v1.z), x13 = bf2f(v1.w);
            float x20 = bf2f(v2.x), x21 = bf2f(v2.y), x22 = bf2f(v2.z), x23 = bf2f(v2.w);
            float x30 = bf2f(v3.x), x31 = bf2f(v3.y), x32 = bf2f(v3.z), x33 = bf2f(v3.w);
            #pragma unroll
            for (int h = 0; h < HEADS; ++h) {
                acc[h][0] += e0[h] * x00 + e1[h] * x10 + e2[h] * x20 + e3[h] * x30;
                acc[h][1] += e0[h] * x01 + e1[h] * x11 + e2[h] * x21 + e3[h] * x31;
                acc[h][2] += e0[h] * x02 + e1[h] * x12 + e2[h] * x22 + e3[h] * x32;
                acc[h][3] += e0[h] * x03 + e1[h] * x13 + e2[h] * x23 + e3[h] * x33;
            }
        }
        for (; j < nv; ++j) {
            int s = ssrc[j];
            f32x4 e = *(const f32x4*)&se[j * 4];
            ushort4_t xv = *(const ushort4_t*)&x2b[(size_t)s * HC1 + lane * 4];
            float x0 = bf2f(xv.x), x1 = bf2f(xv.y), x2 = bf2f(xv.z), x3 = bf2f(xv.w);
            #pragma unroll
            for (int h = 0; h < HEADS; ++h) {
                acc[h][0] += e[h] * x0; acc[h][1] += e[h] * x1;
                acc[h][2] += e[h] * x2; acc[h][3] += e[h] * x3;
            }
        }
        __syncthreads();
    }
    DEN_REDUCE
    #pragma unroll
    for (int h = 0; h < HEADS; ++h) {
        ushort4_t o;
        o.x = f2bf(acc[h][0] * rd[h]); o.y = f2bf(acc[h][1] * rd[h]);
        o.z = f2bf(acc[h][2] * rd[h]); o.w = f2bf(acc[h][3] * rd[h]);
        *(ushort4_t*)&aggx[(size_t)d * 1024 + h * HC1 + lane * 4] = o;
    }
}

// ---------------------------------------------------------------- launch
extern "C" void kernel_launch(void* const* d_in, const int* in_sizes, int n_in,
                              void* d_out, int out_size, void* d_ws, size_t ws_size,
                              hipStream_t stream) {
    const float* x0   = (const float*)d_in[0];
    const int*   ei   = (const int*)d_in[1];
    const float* W1   = (const float*)d_in[2];
    const float* as1  = (const float*)d_in[3];
    const float* ad1  = (const float*)d_in[4];
    const float* res1 = (const float*)d_in[5];
    const float* b1   = (const float*)d_in[6];
    const float* W2   = (const float*)d_in[7];
    const float* as2  = (const float*)d_in[8];
    const float* ad2  = (const float*)d_in[9];
    const float* res2 = (const float*)d_in[10];
    const float* b2   = (const float*)d_in[11];
    const float* W3   = (const float*)d_in[12];
    const float* as3  = (const float*)d_in[13];
    const float* ad3  = (const float*)d_in[14];
    const float* res3 = (const float*)d_in[15];
    const float* b3   = (const float*)d_in[16];

    char* p = (char*)d_ws;
    auto alloc = [&](size_t bytes) -> void* {
        void* r = (void*)p;
        p += (bytes + 255) & ~(size_t)255;
        return r;
    };
    int*      cnt     = (int*)alloc((size_t)NNODES * 4);
    int*      incl    = (int*)alloc((size_t)NNODES * 4);
    int*      bsums   = (int*)alloc((size_t)SCB * 4);
    int*      row_ptr = (int*)alloc((size_t)(NNODES + 1) * 4);
    int*      cursor  = (int*)alloc((size_t)NNODES * 4);
    int*      csr_src = (int*)alloc((size_t)NTOT * 4);
    float*    als     = (float*)alloc((size_t)NNODES * HEADS * 4);
    float*    ald     = (float*)alloc((size_t)NNODES * HEADS * 4);
    float*    als3    = (float*)alloc((size_t)NNODES * HEADS * 4);
    float*    ald3    = (float*)alloc((size_t)NNODES * HEADS * 4);
    ushort_t* x0b     = (ushort_t*)alloc((size_t)NNODES * KPAD1 * 2);
    ushort_t* x2      = (ushort_t*)alloc((size_t)NNODES * HC1 * 2);
    ushort_t* Bt1     = (ushort_t*)alloc((size_t)HC1 * K1S * 2);
    ushort_t* Bt2     = (ushort_t*)alloc((size_t)N2S * HC1 * 2);
    float*    bias512 = (float*)alloc((size_t)N2S * 4);
    ushort_t* Bt3     = (ushort_t*)alloc((size_t)NC * K3S * 2);
    float*    w_as1   = (float*)alloc((size_t)KPAD1 * 4 * 4);
    float*    w_ad1   = (float*)alloc((size_t)KPAD1 * 4 * 4);
    float*    w_as2   = (float*)alloc((size_t)HC1 * 4 * 4);
    float*    w_ad2   = (float*)alloc((size_t)HC1 * 4 * 4);
    float*    w_as3   = (float*)alloc((size_t)HC1 * 4 * 4);
    float*    w_ad3   = (float*)alloc((size_t)HC1 * 4 * 4);
    // aliased region: layer-1/2 temporaries, reused as aggx3 [N,1024] bf16 (102.4 MB)
    char*     big     = (char*)alloc((size_t)NNODES * 1024 * 2);
    ushort_t* aggx1   = (ushort_t*)big;                                  // [N,256]
    ushort_t* x1      = (ushort_t*)(big + (size_t)NNODES * HC1 * 2);     // [N,256]
    ushort_t* comb    = (ushort_t*)(big + (size_t)NNODES * HC1 * 4);     // [N,512]
    ushort_t* aggx3   = (ushort_t*)big;                                  // [N,1024] (layer 3)

    hipMemsetAsync(cnt, 0, (size_t)NNODES * 4, stream);

    int tb = 256;
    int nscan = (NNODES + SCB - 1) / SCB;
    count_kernel<<<(NTOT + tb - 1) / tb, tb, 0, stream>>>(ei, cnt);
    scan1_kernel<<<nscan, SCB, 0, stream>>>(cnt, incl, bsums, NNODES);
    scan2_kernel<<<1, SCB, 0, stream>>>(bsums, nscan);
    scan3_kernel<<<nscan, SCB, 0, stream>>>(cnt, incl, bsums, row_ptr, cursor, NNODES);
    scatter_kernel<<<(NTOT + tb - 1) / tb, tb, 0, stream>>>(ei, cursor, csr_src);

    prep_kernel<<<(PREP_TOTAL + 255) / 256, 256, 0, stream>>>(
        x0, W1, res1, W2, res2, W3, res3, as1, ad1, as2, ad2, as3, ad3, b2,
        x0b, Bt1, Bt2, Bt3, bias512, w_as1, w_ad1, w_as2, w_ad2, w_as3, w_ad3);

    auto gemm = [&](const ushort_t* A1, int lda1, const ushort_t* A2, int lda2, int Ksplit,
                    const ushort_t* Bt, const float* bias,
                    float* Cf, ushort_t* Cb, int M, int Nn, int K, int relu) {
        dim3 g((Nn + BN - 1) / BN, (M + BM - 1) / BM);
        gemm_mfma_kernel<<<g, 256, 0, stream>>>(A1, lda1, A2, lda2, Ksplit, Bt, bias,
                                                Cf, Cb, M, Nn, K, relu);
    };

    // ---- layer 1 (aggregate-then-transform; GEMM reads [aggx1 | x0b])
    logits_gemv_kernel<<<NNODES, 64, 0, stream>>>(x0b, KPAD1, w_as1, w_ad1, als, ald);
    agg1_kernel<<<NNODES, 64, 0, stream>>>(x0b, als, ald, row_ptr, csr_src, aggx1);
    gemm(aggx1, HC1, x0b, KPAD1, HC1, Bt1, b1, nullptr, x1, NNODES, HC1, K1S, 1);

    // ---- layer 2 (stacked GEMM [h2|resid]; agg2 also emits layer-3 logits)
    gemm(x1, HC1, x1, HC1, HC1, Bt2, bias512, nullptr, comb, NNODES, N2S, HC1, 0);
    logits_gemv_kernel<<<NNODES, 64, 0, stream>>>(x1, HC1, w_as2, w_ad2, als, ald);
    agg2_kernel<<<NNODES, 64, 0, stream>>>(comb, als, ald, row_ptr, csr_src,
                                           w_as3, w_ad3, x2, als3, ald3);

    // ---- layer 3 (aggregate-then-transform; GEMM reads [aggx3 | x2])
    agg3_kernel<<<NNODES, 64, 0, stream>>>(x2, als3, ald3, row_ptr, csr_src, aggx3);
    gemm(aggx3, 1024, x2, HC1, 1024, Bt3, b3, (float*)d_out, nullptr, NNODES, NC, K3S, 0);
}